// Round 19
// baseline (168.615 us; speedup 1.0000x reference)
//
#include <hip/hip_runtime.h>
#include <math.h>

#define BH 64
#define NN 8192
#define DD 64
#define MM 32

#define NROWS (BH*NN)            // 524288
#define NORMC 0.35355339059327379f   // 64^-0.25
#define RATIO 0.17677669529663689f   // 32^-0.5
#define EPSK  1e-4f
#define DIAGC 0.0625f                // 0.5 * 64^-0.5

#define CPB 64                   // chunks per batch
#define CHUNK 128                // rows per chunk (32 per wave, ONE nb)
#define K12_BLOCKS (BH*CPB)      // 4096

typedef __attribute__((ext_vector_type(8))) short short8;
typedef __attribute__((ext_vector_type(4))) float f32x4;

union FragU { uint4 u; short8 s; };

// round-to-nearest-even fp32 -> bf16 (bits in low 16)
__device__ __forceinline__ unsigned bf16r(float x) {
  unsigned u = __float_as_uint(x);
  return (u + 0x7fffu + ((u >> 16) & 1u)) >> 16;
}
// 8 fp32 -> hi/lo bf16x8 fragments (split: x = hi + lo)
__device__ __forceinline__ void cvt8(const float* f, FragU& hi, FragU& lo) {
  unsigned h[8], lw[8];
  #pragma unroll
  for (int j = 0; j < 8; ++j) {
    h[j] = bf16r(f[j]);
    lw[j] = bf16r(f[j] - __uint_as_float(h[j] << 16));
  }
  hi.u = make_uint4(h[0]|(h[1]<<16),  h[2]|(h[3]<<16),  h[4]|(h[5]<<16),  h[6]|(h[7]<<16));
  lo.u = make_uint4(lw[0]|(lw[1]<<16), lw[2]|(lw[3]<<16), lw[4]|(lw[5]<<16), lw[6]|(lw[7]<<16));
}

#define MFMA(a,b,c) __builtin_amdgcn_mfma_f32_16x16x32_bf16((a),(b),(c),0,0,0)

__device__ __forceinline__ float wave_max(float v) {
  #pragma unroll
  for (int off = 32; off > 0; off >>= 1)
    v = fmaxf(v, __shfl_down(v, off, 64));
  return v;
}

// ---------------- proj fragments: hi/lo bf16x8 per (mt,ks,lane) -------------
// B-frag (16x16x32): lane l holds B[k=(l>>4)*8+j][n=l&15]; B = proj^T so
// value = proj[mt*16 + (l&15)][ks*32 + (l>>4)*8 + j].
__global__ void kfrag_proj(const float* __restrict__ proj,
                           uint4* __restrict__ pfH, uint4* __restrict__ pfL)
{
  const int t = threadIdx.x;
  const int l = t & 63, g = t >> 6;          // g = mt*2 + ks
  const int mt = g >> 1, ks = g & 1;
  const int lr = l & 15, lg = l >> 4;
  float f[8];
  #pragma unroll
  for (int j = 0; j < 8; ++j)
    f[j] = proj[(mt*16 + lr)*DD + ks*32 + lg*8 + j];
  FragU hi, lo; cvt8(f, hi, lo);
  pfH[g*64 + l] = hi.u;
  pfL[g*64 + l] = lo.u;
}

// ---------------- K12: FUSED — dash MFMA -> E' (LDS bf16) -> kv MFMA --------
// R19 = R16 best config (grid-backfill, (256,3), laundered pf loads,
// single-buffer staging) with CHUNK=128: each wave does ONE 32-row nb, so
// its eh/el staging is written once and read once — the R18 WAR hazard is
// gone STRUCTURALLY with zero extra registers/LDS. 4096 blocks -> finer
// backfill, shorter per-block serial chain.
__global__ __launch_bounds__(256, 3) void k12_kv(
    const float* __restrict__ k, const float* __restrict__ v,
    const uint4* __restrict__ pfH, const uint4* __restrict__ pfL,
    float* __restrict__ kvPart, float* __restrict__ ksPart,
    float* __restrict__ vsPart, float* __restrict__ partialMax)
{
  __shared__ float red[8192];      // 32 KB: aliased E' staging, then reductions
  __shared__ float wmaxL[4];
  const int t = threadIdx.x;
  const int w = t >> 6, l = t & 63;
  const int lr = l & 15, lg = l >> 4;
  const int blk = blockIdx.x;
  const int b = blk >> 6, c = blk & (CPB - 1);
  const size_t nrow0 = (size_t)b * NN + (size_t)c * CHUNK + (size_t)w * 32;

  ushort* eh = (ushort*)red + w * 2560;   // [32 m][40] hi  (2560B/wave)
  ushort* el = eh + 1280;                 // [32 m][40] lo

  f32x4 accK[2][4];
  #pragma unroll
  for (int mt = 0; mt < 2; ++mt)
    #pragma unroll
    for (int dt = 0; dt < 4; ++dt)
      accK[mt][dt] = (f32x4){0.f, 0.f, 0.f, 0.f};
  float ksacc0 = 0.f, ksacc1 = 0.f;
  float vsum[4] = {0.f, 0.f, 0.f, 0.f};
  float tmax = -3.4e38f;

  // ---- phase A: E' for this wave's 32 rows (MFMA dash), staged to LDS
  #pragma unroll
  for (int rt = 0; rt < 2; ++rt) {
    float sq = 0.f;
    f32x4 a0 = {0.f,0.f,0.f,0.f}, a1 = {0.f,0.f,0.f,0.f};
    #pragma unroll
    for (int ks = 0; ks < 2; ++ks) {
      const float4* src = (const float4*)(k + (nrow0 + rt*16 + lr)*DD + ks*32 + lg*8);
      float4 x0 = src[0], x1 = src[1];
      float qv[8] = {x0.x,x0.y,x0.z,x0.w, x1.x,x1.y,x1.z,x1.w};
      #pragma unroll
      for (int j = 0; j < 8; ++j) sq += qv[j]*qv[j];
      FragU aH, aL; cvt8(qv, aH, aL);     // live only inside this ks

      // laundered per-ks proj-frag loads (16 regs live, not hoistable)
      uintptr_t pfh_ = (uintptr_t)pfH, pfl_ = (uintptr_t)pfL;
      asm volatile("" : "+s"(pfh_), "+s"(pfl_));
      const uint4* pH = (const uint4*)pfh_;
      const uint4* pL = (const uint4*)pfl_;
      FragU pH0, pH1, pL0, pL1;
      pH0.u = pH[ks*64 + l];          // mt=0: g = 0*2+ks
      pH1.u = pH[(2+ks)*64 + l];      // mt=1: g = 1*2+ks
      pL0.u = pL[ks*64 + l];
      pL1.u = pL[(2+ks)*64 + l];

      a0 = MFMA(aL.s, pH0.s, a0);
      a0 = MFMA(aH.s, pL0.s, a0);
      a0 = MFMA(aH.s, pH0.s, a0);
      a1 = MFMA(aL.s, pH1.s, a1);
      a1 = MFMA(aH.s, pL1.s, a1);
      a1 = MFMA(aH.s, pH1.s, a1);
    }
    sq += __shfl_xor(sq, 16, 64);
    sq += __shfl_xor(sq, 32, 64);
    unsigned h0w[4], l0w[4], h1w[4], l1w[4];
    #pragma unroll
    for (int reg = 0; reg < 4; ++reg) {
      const float diag = DIAGC * __shfl(sq, lg*4 + reg, 64);
      const float d0 = a0[reg] * NORMC;
      const float d1 = a1[reg] * NORMC;
      tmax = fmaxf(tmax, fmaxf(d0, d1));
      const float e0 = __expf(d0 - diag);
      const float e1 = __expf(d1 - diag);
      ksacc0 += e0;                      // col m = lr
      ksacc1 += e1;                      // col m = lr+16
      h0w[reg] = bf16r(e0);
      l0w[reg] = bf16r(e0 - __uint_as_float(h0w[reg] << 16));
      h1w[reg] = bf16r(e1);
      l1w[reg] = bf16r(e1 - __uint_as_float(h1w[reg] << 16));
    }
    const int nloc = rt*16 + lg*4;       // 4 consecutive ushorts, 4B-aligned
    *(unsigned*)(eh + lr*40      + nloc)     = h0w[0] | (h0w[1] << 16);
    *(unsigned*)(eh + lr*40      + nloc + 2) = h0w[2] | (h0w[3] << 16);
    *(unsigned*)(el + lr*40      + nloc)     = l0w[0] | (l0w[1] << 16);
    *(unsigned*)(el + lr*40      + nloc + 2) = l0w[2] | (l0w[3] << 16);
    *(unsigned*)(eh + (lr+16)*40 + nloc)     = h1w[0] | (h1w[1] << 16);
    *(unsigned*)(eh + (lr+16)*40 + nloc + 2) = h1w[2] | (h1w[3] << 16);
    *(unsigned*)(el + (lr+16)*40 + nloc)     = l1w[0] | (l1w[1] << 16);
    *(unsigned*)(el + (lr+16)*40 + nloc + 2) = l1w[2] | (l1w[3] << 16);
  }

  // ---- phase B: kv += E'^T x v via MFMA (A from LDS, B from global)
  #pragma unroll
  for (int dt = 0; dt < 4; ++dt) {
    float vv[8];
    #pragma unroll
    for (int j = 0; j < 8; ++j)
      vv[j] = v[(nrow0 + lg*8 + j)*DD + dt*16 + lr];
    vsum[dt] += vv[0]+vv[1]+vv[2]+vv[3]+vv[4]+vv[5]+vv[6]+vv[7];
    FragU bHv, bLv; cvt8(vv, bHv, bLv);
    #pragma unroll
    for (int mt = 0; mt < 2; ++mt) {
      FragU aHk, aLk;
      aHk.u = *(const uint4*)(eh + (mt*16 + lr)*40 + lg*8);
      aLk.u = *(const uint4*)(el + (mt*16 + lr)*40 + lg*8);
      accK[mt][dt] = MFMA(aLk.s, bHv.s, accK[mt][dt]);
      accK[mt][dt] = MFMA(aHk.s, bLv.s, accK[mt][dt]);
      accK[mt][dt] = MFMA(aHk.s, bHv.s, accK[mt][dt]);
    }
  }

  // ---- epilogue: block max + reductions
  tmax = wave_max(tmax);
  if (l == 0) wmaxL[w] = tmax;
  ksacc0 += __shfl_xor(ksacc0, 16, 64);
  ksacc0 += __shfl_xor(ksacc0, 32, 64);
  ksacc1 += __shfl_xor(ksacc1, 16, 64);
  ksacc1 += __shfl_xor(ksacc1, 32, 64);
  #pragma unroll
  for (int dt = 0; dt < 4; ++dt) {
    vsum[dt] += __shfl_xor(vsum[dt], 16, 64);
    vsum[dt] += __shfl_xor(vsum[dt], 32, 64);
  }
  __syncthreads();                 // everyone done with E' staging
  // red layout [o][w] (o = m*64+d): lanes same inst -> banks 4lr+w, 2-way max
  #pragma unroll
  for (int mt = 0; mt < 2; ++mt)
    #pragma unroll
    for (int dt = 0; dt < 4; ++dt)
      #pragma unroll
      for (int reg = 0; reg < 4; ++reg)
        red[((mt*16 + lg*4 + reg)*64 + dt*16 + lr)*4 + w] = accK[mt][dt][reg];
  __syncthreads();
  if (t == 0)
    partialMax[blk] = fmaxf(fmaxf(wmaxL[0], wmaxL[1]), fmaxf(wmaxL[2], wmaxL[3]));
  #pragma unroll
  for (int ii = 0; ii < 8; ++ii) {
    const int o = t + 256 * ii;
    const float4 r4 = *(const float4*)&red[o*4];
    kvPart[(size_t)blk * 2048 + o] = r4.x + r4.y + r4.z + r4.w;
  }
  __syncthreads();
  if (l < 16) {
    red[w*32 + lr]        = ksacc0;
    red[w*32 + 16 + lr]   = ksacc1;
    #pragma unroll
    for (int dt = 0; dt < 4; ++dt)
      red[128 + w*64 + dt*16 + lr] = vsum[dt];
  }
  __syncthreads();
  if (t < 32)
    ksPart[blk*32 + t] = red[t] + red[32+t] + red[64+t] + red[96+t];
  if (t < 64)
    vsPart[blk*64 + t] = red[128+t] + red[192+t] + red[256+t] + red[320+t];
}

// ---------------- K1b: reduce partial maxes (4096) -> global max ------------
__global__ __launch_bounds__(256) void k1b_reduce_max(
    const float* __restrict__ partialMax, float* __restrict__ gmax)
{
  const int t = threadIdx.x;
  float mx = -3.4e38f;
  for (int i = t; i < K12_BLOCKS; i += 256) mx = fmaxf(mx, partialMax[i]);
  mx = wave_max(mx);
  __shared__ float wmaxs[4];
  if ((t & 63) == 0) wmaxs[t >> 6] = mx;
  __syncthreads();
  if (t == 0)
    *gmax = fmaxf(fmaxf(wmaxs[0], wmaxs[1]), fmaxf(wmaxs[2], wmaxs[3]));
}

// ---------------- K2b: reduce -> kv values (LDS) -> ksF + kv B-fragments ----
__global__ __launch_bounds__(256) void k2b_reduce(
    const float* __restrict__ kvPart, const float* __restrict__ ksPart,
    const float* __restrict__ vsPart, const float* __restrict__ gmaxPtr,
    float* __restrict__ ksF, uint4* __restrict__ kfH, uint4* __restrict__ kfL)
{
  __shared__ float vsumL[64];
  __shared__ float kvL[2048];
  const int b = blockIdx.x, t = threadIdx.x;
  const float scale = __expf(-*gmaxPtr);
  if (t < 64) {
    float s = 0.f;
    for (int c = 0; c < CPB; ++c)
      s += vsPart[(b * CPB + c) * 64 + t];
    vsumL[t] = s;
  }
  __syncthreads();
  #pragma unroll
  for (int ii = 0; ii < 8; ++ii) {
    const int o = t + 256 * ii;
    float s = 0.f;
    for (int c = 0; c < CPB; ++c)
      s += kvPart[((size_t)(b * CPB + c)) * 2048 + o];
    kvL[o] = RATIO * (scale * s + EPSK * vsumL[o & 63]);
  }
  if (t < 32) {
    float s = 0.f;
    for (int c = 0; c < CPB; ++c)
      s += ksPart[(b * CPB + c) * 32 + t];
    ksF[b * 32 + t] = RATIO * (scale * s + EPSK * (float)NN);
  }
  __syncthreads();
  // B-frag (16x16x32): lane l holds kv[k=(l>>4)*8+j][d = dt*16 + (l&15)]
  {
    const int l = t & 63, dt = t >> 6;
    const int lr = l & 15, lg = l >> 4;
    float f[8];
    #pragma unroll
    for (int j = 0; j < 8; ++j)
      f[j] = kvL[(lg*8 + j)*64 + dt*16 + lr];
    FragU hi, lo; cvt8(f, hi, lo);
    kfH[(b*4 + dt)*64 + l] = hi.u;
    kfL[(b*4 + dt)*64 + l] = lo.u;
  }
}

// ---------------- K3: dash MFMA -> softmax -> num MFMA (barrier-free) -------
__global__ __launch_bounds__(256, 4) void k3_out(
    const float* __restrict__ q,
    const uint4* __restrict__ pfH, const uint4* __restrict__ pfL,
    const uint4* __restrict__ kfH, const uint4* __restrict__ kfL,
    const float* __restrict__ ksF, float* __restrict__ out)
{
  __shared__ float dashL[256][36];   // fp32 dash; reused per-row as packed pstar
  __shared__ float ssqL[256][4];
  const int t = threadIdx.x;
  const int w = t >> 6, l = t & 63;
  const int lr = l & 15, lg = l >> 4;
  const int b = blockIdx.x >> 5;
  const size_t rowBase = (size_t)blockIdx.x * 256;
  const int wrb = w * 64;

  FragU pbH[2][2], pbL[2][2];
  #pragma unroll
  for (int mt = 0; mt < 2; ++mt)
    #pragma unroll
    for (int ks = 0; ks < 2; ++ks) {
      pbH[mt][ks].u = pfH[(mt*2+ks)*64 + l];
      pbL[mt][ks].u = pfL[(mt*2+ks)*64 + l];
    }

  // phase A
  #pragma unroll
  for (int rt = 0; rt < 4; ++rt) {
    const int rrow = wrb + rt*16 + lr;
    f32x4 acc0 = {0.f,0.f,0.f,0.f}, acc1 = {0.f,0.f,0.f,0.f};
    float sq = 0.f;
    #pragma unroll
    for (int ks = 0; ks < 2; ++ks) {
      const float4* src = (const float4*)(q + (rowBase + rrow)*DD + ks*32 + lg*8);
      float4 a0 = src[0], a1 = src[1];
      float qv[8] = {a0.x,a0.y,a0.z,a0.w, a1.x,a1.y,a1.z,a1.w};
      #pragma unroll
      for (int j = 0; j < 8; ++j) sq += qv[j]*qv[j];
      FragU aH, aL; cvt8(qv, aH, aL);
      acc0 = MFMA(aL.s, pbH[0][ks].s, acc0);
      acc0 = MFMA(aH.s, pbL[0][ks].s, acc0);
      acc0 = MFMA(aH.s, pbH[0][ks].s, acc0);
      acc1 = MFMA(aL.s, pbH[1][ks].s, acc1);
      acc1 = MFMA(aH.s, pbL[1][ks].s, acc1);
      acc1 = MFMA(aH.s, pbH[1][ks].s, acc1);
    }
    ssqL[rrow][lg] = sq;
    #pragma unroll
    for (int reg = 0; reg < 4; ++reg) {
      dashL[wrb + rt*16 + lg*4 + reg][lr]      = acc0[reg];
      dashL[wrb + rt*16 + lg*4 + reg][16 + lr] = acc1[reg];
    }
  }

  // softmax phase: thread t owns row t (same wave as its stripe: no barrier)
  {
    float dv[32];
    const float4* dr = (const float4*)&dashL[t][0];
    #pragma unroll
    for (int i = 0; i < 8; ++i) {
      float4 v4 = dr[i];
      dv[4*i]=v4.x; dv[4*i+1]=v4.y; dv[4*i+2]=v4.z; dv[4*i+3]=v4.w;
    }
    const float ssq = ssqL[t][0]+ssqL[t][1]+ssqL[t][2]+ssqL[t][3];
    float mx = -3.4e38f;
    #pragma unroll
    for (int m = 0; m < MM; ++m) { dv[m] *= NORMC; mx = fmaxf(mx, dv[m]); }
    const float sub = DIAGC * ssq + mx;
    const float* __restrict__ ksb = ksF + b * 32;
    float den = 0.f;
    #pragma unroll
    for (int m = 0; m < MM; ++m) {
      dv[m] = RATIO * (__expf(dv[m] - sub) + EPSK);
      den = fmaf(dv[m], ksb[m], den);
    }
    const float inv = 1.0f / den;
    unsigned hiw[16], low[16];
    #pragma unroll
    for (int u = 0; u < 16; ++u) {
      const float x0 = dv[2*u] * inv, x1 = dv[2*u+1] * inv;
      const unsigned h0 = bf16r(x0);
      const unsigned l0 = bf16r(x0 - __uint_as_float(h0 << 16));
      const unsigned h1 = bf16r(x1);
      const unsigned l1 = bf16r(x1 - __uint_as_float(h1 << 16));
      hiw[u] = h0 | (h1 << 16);
      low[u] = l0 | (l1 << 16);
    }
    uint4* pr = (uint4*)&dashL[t][0];   // overwrite own row only
    pr[0] = make_uint4(hiw[0],hiw[1],hiw[2],hiw[3]);
    pr[1] = make_uint4(hiw[4],hiw[5],hiw[6],hiw[7]);
    pr[2] = make_uint4(hiw[8],hiw[9],hiw[10],hiw[11]);
    pr[3] = make_uint4(hiw[12],hiw[13],hiw[14],hiw[15]);
    pr[4] = make_uint4(low[0],low[1],low[2],low[3]);
    pr[5] = make_uint4(low[4],low[5],low[6],low[7]);
    pr[6] = make_uint4(low[8],low[9],low[10],low[11]);
    pr[7] = make_uint4(low[12],low[13],low[14],low[15]);
  }

  // phase B: out = pstar · kv (K=32, one k-step, 3 comp terms)
  FragU kbH[4], kbL[4];
  #pragma unroll
  for (int dt = 0; dt < 4; ++dt) {
    kbH[dt].u = kfH[(b*4 + dt)*64 + l];
    kbL[dt].u = kfL[(b*4 + dt)*64 + l];
  }
  #pragma unroll
  for (int rt = 0; rt < 4; ++rt) {
    const uint4* pr = (const uint4*)&dashL[wrb + rt*16 + lr][0];
    FragU aH, aL;
    aH.u = pr[lg];
    aL.u = pr[4 + lg];
    #pragma unroll
    for (int dt = 0; dt < 4; ++dt) {
      f32x4 o = {0.f,0.f,0.f,0.f};
      o = MFMA(aL.s, kbH[dt].s, o);
      o = MFMA(aH.s, kbL[dt].s, o);
      o = MFMA(aH.s, kbH[dt].s, o);
      float* ob = out + (rowBase + wrb + rt*16 + lg*4)*DD + dt*16 + lr;
      ob[0]      = o[0];
      ob[DD]     = o[1];
      ob[2*DD]   = o[2];
      ob[3*DD]   = o[3];
    }
  }
}

// ---------------- host ------------------------------------------------------
extern "C" void kernel_launch(void* const* d_in, const int* in_sizes, int n_in,
                              void* d_out, int out_size, void* d_ws, size_t ws_size,
                              hipStream_t stream) {
  const float* q    = (const float*)d_in[0];
  const float* k    = (const float*)d_in[1];
  const float* v    = (const float*)d_in[2];
  const float* proj = (const float*)d_in[3];
  float* out = (float*)d_out;
  float* ws  = (float*)d_ws;

  float*    partialMax = ws;                       // 4096
  float*    gmax       = ws + 4096;                // (pad to 8192)
  float*    kvPart     = ws + 8192;                // 4096*2048
  float*    ksPart     = kvPart + 8388608;         // 4096*32
  float*    vsPart     = ksPart + 131072;          // 4096*64
  float*    ksF        = vsPart + 262144;          // 64*32 (pad 2048)
  unsigned* pfH        = (unsigned*)(ksF + 2048);  // 4*64 uint4 = 1024 words
  unsigned* pfL        = pfH + 1024;               // 1024
  unsigned* kfH        = pfL + 1024;               // 64*4*64 uint4 = 65536 words
  unsigned* kfL        = kfH + 65536;              // 65536

  kfrag_proj<<<1, 256, 0, stream>>>(proj, (uint4*)pfH, (uint4*)pfL);
  k12_kv<<<K12_BLOCKS, 256, 0, stream>>>(k, v, (uint4*)pfH, (uint4*)pfL,
                                         kvPart, ksPart, vsPart, partialMax);
  k1b_reduce_max<<<1, 256, 0, stream>>>(partialMax, gmax);
  k2b_reduce<<<BH, 256, 0, stream>>>(kvPart, ksPart, vsPart, gmax,
                                     ksF, (uint4*)kfH, (uint4*)kfL);
  k3_out<<<NROWS / 256, 256, 0, stream>>>(q, (uint4*)pfH, (uint4*)pfL,
                                          (uint4*)kfH, (uint4*)kfL, ksF, out);
}

// Round 20
// 156.230 us; speedup vs baseline: 1.0793x; 1.0793x over previous
//
#include <hip/hip_runtime.h>
#include <math.h>

#define BH 64
#define NN 8192
#define DD 64
#define MM 32

#define NROWS (BH*NN)            // 524288
#define NORMC 0.35355339059327379f   // 64^-0.25
#define RATIO 0.17677669529663689f   // 32^-0.5
#define EPSK  1e-4f
#define DIAGC 0.0625f                // 0.5 * 64^-0.5

#define CPB 64                   // chunks per batch
#define CHUNK 128                // rows per chunk (32 per wave, ONE nb)
#define K12_BLOCKS (BH*CPB)      // 4096

typedef __attribute__((ext_vector_type(8))) short short8;
typedef __attribute__((ext_vector_type(4))) float f32x4;

union FragU { uint4 u; short8 s; };

// round-to-nearest-even fp32 -> bf16 (bits in low 16)
__device__ __forceinline__ unsigned bf16r(float x) {
  unsigned u = __float_as_uint(x);
  return (u + 0x7fffu + ((u >> 16) & 1u)) >> 16;
}
// 8 fp32 -> hi/lo bf16x8 fragments (split: x = hi + lo)
__device__ __forceinline__ void cvt8(const float* f, FragU& hi, FragU& lo) {
  unsigned h[8], lw[8];
  #pragma unroll
  for (int j = 0; j < 8; ++j) {
    h[j] = bf16r(f[j]);
    lw[j] = bf16r(f[j] - __uint_as_float(h[j] << 16));
  }
  hi.u = make_uint4(h[0]|(h[1]<<16),  h[2]|(h[3]<<16),  h[4]|(h[5]<<16),  h[6]|(h[7]<<16));
  lo.u = make_uint4(lw[0]|(lw[1]<<16), lw[2]|(lw[3]<<16), lw[4]|(lw[5]<<16), lw[6]|(lw[7]<<16));
}

#define MFMA(a,b,c) __builtin_amdgcn_mfma_f32_16x16x32_bf16((a),(b),(c),0,0,0)

__device__ __forceinline__ float wave_max(float v) {
  #pragma unroll
  for (int off = 32; off > 0; off >>= 1)
    v = fmaxf(v, __shfl_down(v, off, 64));
  return v;
}

// ---------------- proj fragments: hi/lo bf16x8 per (mt,ks,lane) -------------
__global__ void kfrag_proj(const float* __restrict__ proj,
                           uint4* __restrict__ pfH, uint4* __restrict__ pfL)
{
  const int t = threadIdx.x;
  const int l = t & 63, g = t >> 6;          // g = mt*2 + ks
  const int mt = g >> 1, ks = g & 1;
  const int lr = l & 15, lg = l >> 4;
  float f[8];
  #pragma unroll
  for (int j = 0; j < 8; ++j)
    f[j] = proj[(mt*16 + lr)*DD + ks*32 + lg*8 + j];
  FragU hi, lo; cvt8(f, hi, lo);
  pfH[g*64 + l] = hi.u;
  pfL[g*64 + l] = lo.u;
}

// ---------------- K12: FUSED — dash MFMA -> E' (LDS bf16) -> kv MFMA --------
// R20 = R19 structure (1-nb waves, grid 4096, laundered pf loads) with
// launch_bounds(256,4): the lean 1-nb body measured 64 VGPR + 32 AGPR = 96
// unified <= 128 budget -> no spill expected (R14/R15 spills were the fatter
// 2-nb body). LDS 33KB -> 4 blocks/CU = 4 waves/SIMD.
__global__ __launch_bounds__(256, 4) void k12_kv(
    const float* __restrict__ k, const float* __restrict__ v,
    const uint4* __restrict__ pfH, const uint4* __restrict__ pfL,
    float* __restrict__ kvPart, float* __restrict__ ksPart,
    float* __restrict__ vsPart, float* __restrict__ partialMax)
{
  __shared__ float red[8192];      // 32 KB: aliased E' staging, then reductions
  __shared__ float wmaxL[4];
  const int t = threadIdx.x;
  const int w = t >> 6, l = t & 63;
  const int lr = l & 15, lg = l >> 4;
  const int blk = blockIdx.x;
  const int b = blk >> 6, c = blk & (CPB - 1);
  const size_t nrow0 = (size_t)b * NN + (size_t)c * CHUNK + (size_t)w * 32;

  ushort* eh = (ushort*)red + w * 2560;   // [32 m][40] hi  (2560B/wave)
  ushort* el = eh + 1280;                 // [32 m][40] lo

  f32x4 accK[2][4];
  #pragma unroll
  for (int mt = 0; mt < 2; ++mt)
    #pragma unroll
    for (int dt = 0; dt < 4; ++dt)
      accK[mt][dt] = (f32x4){0.f, 0.f, 0.f, 0.f};
  float ksacc0 = 0.f, ksacc1 = 0.f;
  float vsum[4] = {0.f, 0.f, 0.f, 0.f};
  float tmax = -3.4e38f;

  // ---- phase A: E' for this wave's 32 rows (MFMA dash), staged to LDS
  #pragma unroll
  for (int rt = 0; rt < 2; ++rt) {
    float sq = 0.f;
    f32x4 a0 = {0.f,0.f,0.f,0.f}, a1 = {0.f,0.f,0.f,0.f};
    #pragma unroll
    for (int ks = 0; ks < 2; ++ks) {
      const float4* src = (const float4*)(k + (nrow0 + rt*16 + lr)*DD + ks*32 + lg*8);
      float4 x0 = src[0], x1 = src[1];
      float qv[8] = {x0.x,x0.y,x0.z,x0.w, x1.x,x1.y,x1.z,x1.w};
      #pragma unroll
      for (int j = 0; j < 8; ++j) sq += qv[j]*qv[j];
      FragU aH, aL; cvt8(qv, aH, aL);     // live only inside this ks

      // laundered per-ks proj-frag loads (16 regs live, not hoistable)
      uintptr_t pfh_ = (uintptr_t)pfH, pfl_ = (uintptr_t)pfL;
      asm volatile("" : "+s"(pfh_), "+s"(pfl_));
      const uint4* pH = (const uint4*)pfh_;
      const uint4* pL = (const uint4*)pfl_;
      FragU pH0, pH1, pL0, pL1;
      pH0.u = pH[ks*64 + l];          // mt=0: g = 0*2+ks
      pH1.u = pH[(2+ks)*64 + l];      // mt=1: g = 1*2+ks
      pL0.u = pL[ks*64 + l];
      pL1.u = pL[(2+ks)*64 + l];

      a0 = MFMA(aL.s, pH0.s, a0);
      a0 = MFMA(aH.s, pL0.s, a0);
      a0 = MFMA(aH.s, pH0.s, a0);
      a1 = MFMA(aL.s, pH1.s, a1);
      a1 = MFMA(aH.s, pL1.s, a1);
      a1 = MFMA(aH.s, pH1.s, a1);
    }
    sq += __shfl_xor(sq, 16, 64);
    sq += __shfl_xor(sq, 32, 64);
    unsigned h0w[4], l0w[4], h1w[4], l1w[4];
    #pragma unroll
    for (int reg = 0; reg < 4; ++reg) {
      const float diag = DIAGC * __shfl(sq, lg*4 + reg, 64);
      const float d0 = a0[reg] * NORMC;
      const float d1 = a1[reg] * NORMC;
      tmax = fmaxf(tmax, fmaxf(d0, d1));
      const float e0 = __expf(d0 - diag);
      const float e1 = __expf(d1 - diag);
      ksacc0 += e0;                      // col m = lr
      ksacc1 += e1;                      // col m = lr+16
      h0w[reg] = bf16r(e0);
      l0w[reg] = bf16r(e0 - __uint_as_float(h0w[reg] << 16));
      h1w[reg] = bf16r(e1);
      l1w[reg] = bf16r(e1 - __uint_as_float(h1w[reg] << 16));
    }
    const int nloc = rt*16 + lg*4;       // 4 consecutive ushorts, 4B-aligned
    *(unsigned*)(eh + lr*40      + nloc)     = h0w[0] | (h0w[1] << 16);
    *(unsigned*)(eh + lr*40      + nloc + 2) = h0w[2] | (h0w[3] << 16);
    *(unsigned*)(el + lr*40      + nloc)     = l0w[0] | (l0w[1] << 16);
    *(unsigned*)(el + lr*40      + nloc + 2) = l0w[2] | (l0w[3] << 16);
    *(unsigned*)(eh + (lr+16)*40 + nloc)     = h1w[0] | (h1w[1] << 16);
    *(unsigned*)(eh + (lr+16)*40 + nloc + 2) = h1w[2] | (h1w[3] << 16);
    *(unsigned*)(el + (lr+16)*40 + nloc)     = l1w[0] | (l1w[1] << 16);
    *(unsigned*)(el + (lr+16)*40 + nloc + 2) = l1w[2] | (l1w[3] << 16);
  }

  // ---- phase B: kv += E'^T x v via MFMA (A from LDS, B from global)
  #pragma unroll
  for (int dt = 0; dt < 4; ++dt) {
    float vv[8];
    #pragma unroll
    for (int j = 0; j < 8; ++j)
      vv[j] = v[(nrow0 + lg*8 + j)*DD + dt*16 + lr];
    vsum[dt] += vv[0]+vv[1]+vv[2]+vv[3]+vv[4]+vv[5]+vv[6]+vv[7];
    FragU bHv, bLv; cvt8(vv, bHv, bLv);
    #pragma unroll
    for (int mt = 0; mt < 2; ++mt) {
      FragU aHk, aLk;
      aHk.u = *(const uint4*)(eh + (mt*16 + lr)*40 + lg*8);
      aLk.u = *(const uint4*)(el + (mt*16 + lr)*40 + lg*8);
      accK[mt][dt] = MFMA(aLk.s, bHv.s, accK[mt][dt]);
      accK[mt][dt] = MFMA(aHk.s, bLv.s, accK[mt][dt]);
      accK[mt][dt] = MFMA(aHk.s, bHv.s, accK[mt][dt]);
    }
  }

  // ---- epilogue: block max + reductions
  tmax = wave_max(tmax);
  if (l == 0) wmaxL[w] = tmax;
  ksacc0 += __shfl_xor(ksacc0, 16, 64);
  ksacc0 += __shfl_xor(ksacc0, 32, 64);
  ksacc1 += __shfl_xor(ksacc1, 16, 64);
  ksacc1 += __shfl_xor(ksacc1, 32, 64);
  #pragma unroll
  for (int dt = 0; dt < 4; ++dt) {
    vsum[dt] += __shfl_xor(vsum[dt], 16, 64);
    vsum[dt] += __shfl_xor(vsum[dt], 32, 64);
  }
  __syncthreads();                 // everyone done with E' staging
  // red layout [o][w] (o = m*64+d): lanes same inst -> banks 4lr+w, 2-way max
  #pragma unroll
  for (int mt = 0; mt < 2; ++mt)
    #pragma unroll
    for (int dt = 0; dt < 4; ++dt)
      #pragma unroll
      for (int reg = 0; reg < 4; ++reg)
        red[((mt*16 + lg*4 + reg)*64 + dt*16 + lr)*4 + w] = accK[mt][dt][reg];
  __syncthreads();
  if (t == 0)
    partialMax[blk] = fmaxf(fmaxf(wmaxL[0], wmaxL[1]), fmaxf(wmaxL[2], wmaxL[3]));
  #pragma unroll
  for (int ii = 0; ii < 8; ++ii) {
    const int o = t + 256 * ii;
    const float4 r4 = *(const float4*)&red[o*4];
    kvPart[(size_t)blk * 2048 + o] = r4.x + r4.y + r4.z + r4.w;
  }
  __syncthreads();
  if (l < 16) {
    red[w*32 + lr]        = ksacc0;
    red[w*32 + 16 + lr]   = ksacc1;
    #pragma unroll
    for (int dt = 0; dt < 4; ++dt)
      red[128 + w*64 + dt*16 + lr] = vsum[dt];
  }
  __syncthreads();
  if (t < 32)
    ksPart[blk*32 + t] = red[t] + red[32+t] + red[64+t] + red[96+t];
  if (t < 64)
    vsPart[blk*64 + t] = red[128+t] + red[192+t] + red[256+t] + red[320+t];
}

// ---------------- K1b: reduce partial maxes (4096) -> global max ------------
__global__ __launch_bounds__(256) void k1b_reduce_max(
    const float* __restrict__ partialMax, float* __restrict__ gmax)
{
  const int t = threadIdx.x;
  float mx = -3.4e38f;
  for (int i = t; i < K12_BLOCKS; i += 256) mx = fmaxf(mx, partialMax[i]);
  mx = wave_max(mx);
  __shared__ float wmaxs[4];
  if ((t & 63) == 0) wmaxs[t >> 6] = mx;
  __syncthreads();
  if (t == 0)
    *gmax = fmaxf(fmaxf(wmaxs[0], wmaxs[1]), fmaxf(wmaxs[2], wmaxs[3]));
}

// ---------------- K2b_sum: PARALLEL chunk reduction -> kvF, ksF -------------
// Grid BH*8 = 512 blocks: one output element per thread (coalesced 1KB/inst
// reads), 4-way unrolled c-loop for MLP. Replaces the 64-block serial k2b
// (R19's +25us tail).
__global__ __launch_bounds__(256) void k2b_sum(
    const float* __restrict__ kvPart, const float* __restrict__ ksPart,
    const float* __restrict__ vsPart, const float* __restrict__ gmaxPtr,
    float* __restrict__ kvF, float* __restrict__ ksF)
{
  __shared__ float vsumL[64];
  const int blk = blockIdx.x;
  const int b = blk >> 3, seg = blk & 7;
  const int t = threadIdx.x;
  const float scale = __expf(-*gmaxPtr);
  if (t < 64) {
    float s = 0.f;
    #pragma unroll 4
    for (int c = 0; c < CPB; ++c)
      s += vsPart[(b * CPB + c) * 64 + t];
    vsumL[t] = s;
  }
  __syncthreads();
  const int o = seg * 256 + t;
  float s = 0.f;
  #pragma unroll 4
  for (int c = 0; c < CPB; ++c)
    s += kvPart[((size_t)(b * CPB + c)) * 2048 + o];
  kvF[b * 2048 + o] = RATIO * (scale * s + EPSK * vsumL[o & 63]);
  if (seg == 0 && t < 32) {
    float ks = 0.f;
    #pragma unroll 4
    for (int c = 0; c < CPB; ++c)
      ks += ksPart[(b * CPB + c) * 32 + t];
    ksF[b * 32 + t] = RATIO * (scale * ks + EPSK * (float)NN);
  }
}

// ---------------- K2c: kvF -> kv B-fragments --------------------------------
__global__ __launch_bounds__(256) void k2c_frag(
    const float* __restrict__ kvF,
    uint4* __restrict__ kfH, uint4* __restrict__ kfL)
{
  __shared__ float kvL[2048];
  const int b = blockIdx.x, t = threadIdx.x;
  #pragma unroll
  for (int ii = 0; ii < 8; ++ii)
    kvL[t + 256*ii] = kvF[b*2048 + t + 256*ii];
  __syncthreads();
  // B-frag (16x16x32): lane l holds kv[k=(l>>4)*8+j][d = dt*16 + (l&15)]
  const int l = t & 63, dt = t >> 6;
  const int lr = l & 15, lg = l >> 4;
  float f[8];
  #pragma unroll
  for (int j = 0; j < 8; ++j)
    f[j] = kvL[(lg*8 + j)*64 + dt*16 + lr];
  FragU hi, lo; cvt8(f, hi, lo);
  kfH[(b*4 + dt)*64 + l] = hi.u;
  kfL[(b*4 + dt)*64 + l] = lo.u;
}

// ---------------- K3: dash MFMA -> softmax -> num MFMA (barrier-free) -------
__global__ __launch_bounds__(256, 4) void k3_out(
    const float* __restrict__ q,
    const uint4* __restrict__ pfH, const uint4* __restrict__ pfL,
    const uint4* __restrict__ kfH, const uint4* __restrict__ kfL,
    const float* __restrict__ ksF, float* __restrict__ out)
{
  __shared__ float dashL[256][36];   // fp32 dash; reused per-row as packed pstar
  __shared__ float ssqL[256][4];
  const int t = threadIdx.x;
  const int w = t >> 6, l = t & 63;
  const int lr = l & 15, lg = l >> 4;
  const int b = blockIdx.x >> 5;
  const size_t rowBase = (size_t)blockIdx.x * 256;
  const int wrb = w * 64;

  FragU pbH[2][2], pbL[2][2];
  #pragma unroll
  for (int mt = 0; mt < 2; ++mt)
    #pragma unroll
    for (int ks = 0; ks < 2; ++ks) {
      pbH[mt][ks].u = pfH[(mt*2+ks)*64 + l];
      pbL[mt][ks].u = pfL[(mt*2+ks)*64 + l];
    }

  // phase A
  #pragma unroll
  for (int rt = 0; rt < 4; ++rt) {
    const int rrow = wrb + rt*16 + lr;
    f32x4 acc0 = {0.f,0.f,0.f,0.f}, acc1 = {0.f,0.f,0.f,0.f};
    float sq = 0.f;
    #pragma unroll
    for (int ks = 0; ks < 2; ++ks) {
      const float4* src = (const float4*)(q + (rowBase + rrow)*DD + ks*32 + lg*8);
      float4 a0 = src[0], a1 = src[1];
      float qv[8] = {a0.x,a0.y,a0.z,a0.w, a1.x,a1.y,a1.z,a1.w};
      #pragma unroll
      for (int j = 0; j < 8; ++j) sq += qv[j]*qv[j];
      FragU aH, aL; cvt8(qv, aH, aL);
      acc0 = MFMA(aL.s, pbH[0][ks].s, acc0);
      acc0 = MFMA(aH.s, pbL[0][ks].s, acc0);
      acc0 = MFMA(aH.s, pbH[0][ks].s, acc0);
      acc1 = MFMA(aL.s, pbH[1][ks].s, acc1);
      acc1 = MFMA(aH.s, pbL[1][ks].s, acc1);
      acc1 = MFMA(aH.s, pbH[1][ks].s, acc1);
    }
    ssqL[rrow][lg] = sq;
    #pragma unroll
    for (int reg = 0; reg < 4; ++reg) {
      dashL[wrb + rt*16 + lg*4 + reg][lr]      = acc0[reg];
      dashL[wrb + rt*16 + lg*4 + reg][16 + lr] = acc1[reg];
    }
  }

  // softmax phase: thread t owns row t (same wave as its stripe: no barrier)
  {
    float dv[32];
    const float4* dr = (const float4*)&dashL[t][0];
    #pragma unroll
    for (int i = 0; i < 8; ++i) {
      float4 v4 = dr[i];
      dv[4*i]=v4.x; dv[4*i+1]=v4.y; dv[4*i+2]=v4.z; dv[4*i+3]=v4.w;
    }
    const float ssq = ssqL[t][0]+ssqL[t][1]+ssqL[t][2]+ssqL[t][3];
    float mx = -3.4e38f;
    #pragma unroll
    for (int m = 0; m < MM; ++m) { dv[m] *= NORMC; mx = fmaxf(mx, dv[m]); }
    const float sub = DIAGC * ssq + mx;
    const float* __restrict__ ksb = ksF + b * 32;
    float den = 0.f;
    #pragma unroll
    for (int m = 0; m < MM; ++m) {
      dv[m] = RATIO * (__expf(dv[m] - sub) + EPSK);
      den = fmaf(dv[m], ksb[m], den);
    }
    const float inv = 1.0f / den;
    unsigned hiw[16], low[16];
    #pragma unroll
    for (int u = 0; u < 16; ++u) {
      const float x0 = dv[2*u] * inv, x1 = dv[2*u+1] * inv;
      const unsigned h0 = bf16r(x0);
      const unsigned l0 = bf16r(x0 - __uint_as_float(h0 << 16));
      const unsigned h1 = bf16r(x1);
      const unsigned l1 = bf16r(x1 - __uint_as_float(h1 << 16));
      hiw[u] = h0 | (h1 << 16);
      low[u] = l0 | (l1 << 16);
    }
    uint4* pr = (uint4*)&dashL[t][0];   // overwrite own row only
    pr[0] = make_uint4(hiw[0],hiw[1],hiw[2],hiw[3]);
    pr[1] = make_uint4(hiw[4],hiw[5],hiw[6],hiw[7]);
    pr[2] = make_uint4(hiw[8],hiw[9],hiw[10],hiw[11]);
    pr[3] = make_uint4(hiw[12],hiw[13],hiw[14],hiw[15]);
    pr[4] = make_uint4(low[0],low[1],low[2],low[3]);
    pr[5] = make_uint4(low[4],low[5],low[6],low[7]);
    pr[6] = make_uint4(low[8],low[9],low[10],low[11]);
    pr[7] = make_uint4(low[12],low[13],low[14],low[15]);
  }

  // phase B: out = pstar · kv (K=32, one k-step, 3 comp terms)
  FragU kbH[4], kbL[4];
  #pragma unroll
  for (int dt = 0; dt < 4; ++dt) {
    kbH[dt].u = kfH[(b*4 + dt)*64 + l];
    kbL[dt].u = kfL[(b*4 + dt)*64 + l];
  }
  #pragma unroll
  for (int rt = 0; rt < 4; ++rt) {
    const uint4* pr = (const uint4*)&dashL[wrb + rt*16 + lr][0];
    FragU aH, aL;
    aH.u = pr[lg];
    aL.u = pr[4 + lg];
    #pragma unroll
    for (int dt = 0; dt < 4; ++dt) {
      f32x4 o = {0.f,0.f,0.f,0.f};
      o = MFMA(aL.s, kbH[dt].s, o);
      o = MFMA(aH.s, kbL[dt].s, o);
      o = MFMA(aH.s, kbH[dt].s, o);
      float* ob = out + (rowBase + wrb + rt*16 + lg*4)*DD + dt*16 + lr;
      ob[0]      = o[0];
      ob[DD]     = o[1];
      ob[2*DD]   = o[2];
      ob[3*DD]   = o[3];
    }
  }
}

// ---------------- host ------------------------------------------------------
extern "C" void kernel_launch(void* const* d_in, const int* in_sizes, int n_in,
                              void* d_out, int out_size, void* d_ws, size_t ws_size,
                              hipStream_t stream) {
  const float* q    = (const float*)d_in[0];
  const float* k    = (const float*)d_in[1];
  const float* v    = (const float*)d_in[2];
  const float* proj = (const float*)d_in[3];
  float* out = (float*)d_out;
  float* ws  = (float*)d_ws;

  float*    partialMax = ws;                       // 4096
  float*    gmax       = ws + 4096;                // (pad to 8192)
  float*    kvPart     = ws + 8192;                // 4096*2048
  float*    ksPart     = kvPart + 8388608;         // 4096*32
  float*    vsPart     = ksPart + 131072;          // 4096*64
  float*    ksF        = vsPart + 262144;          // 64*32 (pad 2048)
  float*    kvF        = ksF + 2048;               // 64*2048
  unsigned* pfH        = (unsigned*)(kvF + 131072);// 4*64 uint4 = 1024 words
  unsigned* pfL        = pfH + 1024;               // 1024
  unsigned* kfH        = pfL + 1024;               // 64*4*64 uint4 = 65536 words
  unsigned* kfL        = kfH + 65536;              // 65536

  kfrag_proj<<<1, 256, 0, stream>>>(proj, (uint4*)pfH, (uint4*)pfL);
  k12_kv<<<K12_BLOCKS, 256, 0, stream>>>(k, v, (uint4*)pfH, (uint4*)pfL,
                                         kvPart, ksPart, vsPart, partialMax);
  k1b_reduce_max<<<1, 256, 0, stream>>>(partialMax, gmax);
  k2b_sum<<<BH*8, 256, 0, stream>>>(kvPart, ksPart, vsPart, gmax, kvF, ksF);
  k2c_frag<<<BH, 256, 0, stream>>>(kvF, (uint4*)kfH, (uint4*)kfL);
  k3_out<<<NROWS / 256, 256, 0, stream>>>(q, (uint4*)pfH, (uint4*)pfL,
                                          (uint4*)kfH, (uint4*)kfL, ksF, out);
}

// Round 21
// 154.425 us; speedup vs baseline: 1.0919x; 1.0117x over previous
//
#include <hip/hip_runtime.h>
#include <math.h>

#define BH 64
#define NN 8192
#define DD 64
#define MM 32

#define NROWS (BH*NN)            // 524288
#define NORMC 0.35355339059327379f   // 64^-0.25
#define RATIO 0.17677669529663689f   // 32^-0.5
#define EPSK  1e-4f
#define DIAGC 0.0625f                // 0.5 * 64^-0.5

#define CPB 32                   // chunks per batch
#define CHUNK 256                // rows per chunk (8 waves x 32 rows)
#define K12_BLOCKS (BH*CPB)      // 2048 blocks x 512 threads

typedef __attribute__((ext_vector_type(8))) short short8;
typedef __attribute__((ext_vector_type(4))) float f32x4;

union FragU { uint4 u; short8 s; };

// round-to-nearest-even fp32 -> bf16 (bits in low 16)
__device__ __forceinline__ unsigned bf16r(float x) {
  unsigned u = __float_as_uint(x);
  return (u + 0x7fffu + ((u >> 16) & 1u)) >> 16;
}
// 8 fp32 -> hi/lo bf16x8 fragments (split: x = hi + lo)
__device__ __forceinline__ void cvt8(const float* f, FragU& hi, FragU& lo) {
  unsigned h[8], lw[8];
  #pragma unroll
  for (int j = 0; j < 8; ++j) {
    h[j] = bf16r(f[j]);
    lw[j] = bf16r(f[j] - __uint_as_float(h[j] << 16));
  }
  hi.u = make_uint4(h[0]|(h[1]<<16),  h[2]|(h[3]<<16),  h[4]|(h[5]<<16),  h[6]|(h[7]<<16));
  lo.u = make_uint4(lw[0]|(lw[1]<<16), lw[2]|(lw[3]<<16), lw[4]|(lw[5]<<16), lw[6]|(lw[7]<<16));
}

#define MFMA(a,b,c) __builtin_amdgcn_mfma_f32_16x16x32_bf16((a),(b),(c),0,0,0)

__device__ __forceinline__ float wave_max(float v) {
  #pragma unroll
  for (int off = 32; off > 0; off >>= 1)
    v = fmaxf(v, __shfl_down(v, off, 64));
  return v;
}

// ---------------- proj fragments: hi/lo bf16x8 per (mt,ks,lane) -------------
__global__ void kfrag_proj(const float* __restrict__ proj,
                           uint4* __restrict__ pfH, uint4* __restrict__ pfL)
{
  const int t = threadIdx.x;
  const int l = t & 63, g = t >> 6;          // g = mt*2 + ks
  const int mt = g >> 1, ks = g & 1;
  const int lr = l & 15, lg = l >> 4;
  float f[8];
  #pragma unroll
  for (int j = 0; j < 8; ++j)
    f[j] = proj[(mt*16 + lr)*DD + ks*32 + lg*8 + j];
  FragU hi, lo; cvt8(f, hi, lo);
  pfH[g*64 + l] = hi.u;
  pfL[g*64 + l] = lo.u;
}

// ---------------- K12: FUSED — dash MFMA -> E' (LDS bf16) -> kv MFMA --------
// R21: 8-wave (512-thread) blocks, per-wave body IDENTICAL to R19/R20's
// proven 1-nb version (no spill, VGPR 64+32). LDS = 8 x 5KB staging aliased
// over the 32KB reduction scratch = exactly 40960 B -> 4 blocks/CU, up to
// 32 waves/CU (reg-capped ~20). Grid 2048 -> kvPart back to 17 MB (cheap
// tail). Epilogue: two-stage cross-wave reduction (waves 0-3 write
// red[o*4+w]; waves 4-7 LDS-accumulate into the same slots).
__global__ __launch_bounds__(512, 4) void k12_kv(
    const float* __restrict__ k, const float* __restrict__ v,
    const uint4* __restrict__ pfH, const uint4* __restrict__ pfL,
    float* __restrict__ kvPart, float* __restrict__ ksPart,
    float* __restrict__ vsPart, float* __restrict__ partialMax)
{
  __shared__ float red[10240];     // 40960 B: 8x5KB staging, then reductions
  const int t = threadIdx.x;       // 0..511
  const int w = t >> 6, l = t & 63;
  const int lr = l & 15, lg = l >> 4;
  const int blk = blockIdx.x;
  const int b = blk >> 5, c = blk & (CPB - 1);
  const size_t nrow0 = (size_t)b * NN + (size_t)c * CHUNK + (size_t)w * 32;

  ushort* eh = (ushort*)red + w * 2560;   // [32 m][40] hi  (2560B/wave)
  ushort* el = eh + 1280;                 // [32 m][40] lo

  f32x4 accK[2][4];
  #pragma unroll
  for (int mt = 0; mt < 2; ++mt)
    #pragma unroll
    for (int dt = 0; dt < 4; ++dt)
      accK[mt][dt] = (f32x4){0.f, 0.f, 0.f, 0.f};
  float ksacc0 = 0.f, ksacc1 = 0.f;
  float vsum[4] = {0.f, 0.f, 0.f, 0.f};
  float tmax = -3.4e38f;

  // ---- phase A: E' for this wave's 32 rows (MFMA dash), staged to LDS
  #pragma unroll
  for (int rt = 0; rt < 2; ++rt) {
    float sq = 0.f;
    f32x4 a0 = {0.f,0.f,0.f,0.f}, a1 = {0.f,0.f,0.f,0.f};
    #pragma unroll
    for (int ks = 0; ks < 2; ++ks) {
      const float4* src = (const float4*)(k + (nrow0 + rt*16 + lr)*DD + ks*32 + lg*8);
      float4 x0 = src[0], x1 = src[1];
      float qv[8] = {x0.x,x0.y,x0.z,x0.w, x1.x,x1.y,x1.z,x1.w};
      #pragma unroll
      for (int j = 0; j < 8; ++j) sq += qv[j]*qv[j];
      FragU aH, aL; cvt8(qv, aH, aL);     // live only inside this ks

      // laundered per-ks proj-frag loads (16 regs live, not hoistable)
      uintptr_t pfh_ = (uintptr_t)pfH, pfl_ = (uintptr_t)pfL;
      asm volatile("" : "+s"(pfh_), "+s"(pfl_));
      const uint4* pH = (const uint4*)pfh_;
      const uint4* pL = (const uint4*)pfl_;
      FragU pH0, pH1, pL0, pL1;
      pH0.u = pH[ks*64 + l];          // mt=0: g = 0*2+ks
      pH1.u = pH[(2+ks)*64 + l];      // mt=1: g = 1*2+ks
      pL0.u = pL[ks*64 + l];
      pL1.u = pL[(2+ks)*64 + l];

      a0 = MFMA(aL.s, pH0.s, a0);
      a0 = MFMA(aH.s, pL0.s, a0);
      a0 = MFMA(aH.s, pH0.s, a0);
      a1 = MFMA(aL.s, pH1.s, a1);
      a1 = MFMA(aH.s, pL1.s, a1);
      a1 = MFMA(aH.s, pH1.s, a1);
    }
    sq += __shfl_xor(sq, 16, 64);
    sq += __shfl_xor(sq, 32, 64);
    unsigned h0w[4], l0w[4], h1w[4], l1w[4];
    #pragma unroll
    for (int reg = 0; reg < 4; ++reg) {
      const float diag = DIAGC * __shfl(sq, lg*4 + reg, 64);
      const float d0 = a0[reg] * NORMC;
      const float d1 = a1[reg] * NORMC;
      tmax = fmaxf(tmax, fmaxf(d0, d1));
      const float e0 = __expf(d0 - diag);
      const float e1 = __expf(d1 - diag);
      ksacc0 += e0;                      // col m = lr
      ksacc1 += e1;                      // col m = lr+16
      h0w[reg] = bf16r(e0);
      l0w[reg] = bf16r(e0 - __uint_as_float(h0w[reg] << 16));
      h1w[reg] = bf16r(e1);
      l1w[reg] = bf16r(e1 - __uint_as_float(h1w[reg] << 16));
    }
    const int nloc = rt*16 + lg*4;       // 4 consecutive ushorts, 4B-aligned
    *(unsigned*)(eh + lr*40      + nloc)     = h0w[0] | (h0w[1] << 16);
    *(unsigned*)(eh + lr*40      + nloc + 2) = h0w[2] | (h0w[3] << 16);
    *(unsigned*)(el + lr*40      + nloc)     = l0w[0] | (l0w[1] << 16);
    *(unsigned*)(el + lr*40      + nloc + 2) = l0w[2] | (l0w[3] << 16);
    *(unsigned*)(eh + (lr+16)*40 + nloc)     = h1w[0] | (h1w[1] << 16);
    *(unsigned*)(eh + (lr+16)*40 + nloc + 2) = h1w[2] | (h1w[3] << 16);
    *(unsigned*)(el + (lr+16)*40 + nloc)     = l1w[0] | (l1w[1] << 16);
    *(unsigned*)(el + (lr+16)*40 + nloc + 2) = l1w[2] | (l1w[3] << 16);
  }

  // ---- phase B: kv += E'^T x v via MFMA (A from LDS, B from global)
  #pragma unroll
  for (int dt = 0; dt < 4; ++dt) {
    float vv[8];
    #pragma unroll
    for (int j = 0; j < 8; ++j)
      vv[j] = v[(nrow0 + lg*8 + j)*DD + dt*16 + lr];
    vsum[dt] += vv[0]+vv[1]+vv[2]+vv[3]+vv[4]+vv[5]+vv[6]+vv[7];
    FragU bHv, bLv; cvt8(vv, bHv, bLv);
    #pragma unroll
    for (int mt = 0; mt < 2; ++mt) {
      FragU aHk, aLk;
      aHk.u = *(const uint4*)(eh + (mt*16 + lr)*40 + lg*8);
      aLk.u = *(const uint4*)(el + (mt*16 + lr)*40 + lg*8);
      accK[mt][dt] = MFMA(aLk.s, bHv.s, accK[mt][dt]);
      accK[mt][dt] = MFMA(aHk.s, bLv.s, accK[mt][dt]);
      accK[mt][dt] = MFMA(aHk.s, bHv.s, accK[mt][dt]);
    }
  }

  // ---- epilogue: wave reductions, then two-stage cross-wave reduction
  tmax = wave_max(tmax);
  ksacc0 += __shfl_xor(ksacc0, 16, 64);
  ksacc0 += __shfl_xor(ksacc0, 32, 64);
  ksacc1 += __shfl_xor(ksacc1, 16, 64);
  ksacc1 += __shfl_xor(ksacc1, 32, 64);
  #pragma unroll
  for (int dt = 0; dt < 4; ++dt) {
    vsum[dt] += __shfl_xor(vsum[dt], 16, 64);
    vsum[dt] += __shfl_xor(vsum[dt], 32, 64);
  }
  __syncthreads();                 // all staging reads done; red reusable
  // stage 1: waves 0-3 write their partials; wmax to red[8192+w] (post-barrier
  // scratch beyond the 8192-float reduction area)
  if (w < 4) {
    #pragma unroll
    for (int mt = 0; mt < 2; ++mt)
      #pragma unroll
      for (int dt = 0; dt < 4; ++dt)
        #pragma unroll
        for (int reg = 0; reg < 4; ++reg)
          red[((mt*16 + lg*4 + reg)*64 + dt*16 + lr)*4 + w] = accK[mt][dt][reg];
  }
  if (l == 0) red[8192 + w] = tmax;
  __syncthreads();
  // stage 2: waves 4-7 accumulate into the same slots
  if (w >= 4) {
    #pragma unroll
    for (int mt = 0; mt < 2; ++mt)
      #pragma unroll
      for (int dt = 0; dt < 4; ++dt)
        #pragma unroll
        for (int reg = 0; reg < 4; ++reg)
          red[((mt*16 + lg*4 + reg)*64 + dt*16 + lr)*4 + (w-4)] += accK[mt][dt][reg];
  }
  __syncthreads();
  if (t == 0) {
    float mx = red[8192];
    #pragma unroll
    for (int i = 1; i < 8; ++i) mx = fmaxf(mx, red[8192+i]);
    partialMax[blk] = mx;
  }
  #pragma unroll
  for (int ii = 0; ii < 4; ++ii) {
    const int o = t + 512 * ii;
    const float4 r4 = *(const float4*)&red[o*4];
    kvPart[(size_t)blk * 2048 + o] = r4.x + r4.y + r4.z + r4.w;
  }
  __syncthreads();
  if (l < 16) {
    red[w*32 + lr]        = ksacc0;
    red[w*32 + 16 + lr]   = ksacc1;
    #pragma unroll
    for (int dt = 0; dt < 4; ++dt)
      red[256 + w*64 + dt*16 + lr] = vsum[dt];
  }
  __syncthreads();
  if (t < 32) {
    float s = 0.f;
    #pragma unroll
    for (int ww = 0; ww < 8; ++ww) s += red[ww*32 + t];
    ksPart[blk*32 + t] = s;
  }
  if (t < 64) {
    float s = 0.f;
    #pragma unroll
    for (int ww = 0; ww < 8; ++ww) s += red[256 + ww*64 + t];
    vsPart[blk*64 + t] = s;
  }
}

// ---------------- K1b: reduce partial maxes (2048) -> global max ------------
__global__ __launch_bounds__(256) void k1b_reduce_max(
    const float* __restrict__ partialMax, float* __restrict__ gmax)
{
  const int t = threadIdx.x;
  float mx = -3.4e38f;
  for (int i = t; i < K12_BLOCKS; i += 256) mx = fmaxf(mx, partialMax[i]);
  mx = wave_max(mx);
  __shared__ float wmaxs[4];
  if ((t & 63) == 0) wmaxs[t >> 6] = mx;
  __syncthreads();
  if (t == 0)
    *gmax = fmaxf(fmaxf(wmaxs[0], wmaxs[1]), fmaxf(wmaxs[2], wmaxs[3]));
}

// ---------------- K2b_sum: PARALLEL chunk reduction -> kvF, ksF -------------
__global__ __launch_bounds__(256) void k2b_sum(
    const float* __restrict__ kvPart, const float* __restrict__ ksPart,
    const float* __restrict__ vsPart, const float* __restrict__ gmaxPtr,
    float* __restrict__ kvF, float* __restrict__ ksF)
{
  __shared__ float vsumL[64];
  const int blk = blockIdx.x;
  const int b = blk >> 3, seg = blk & 7;
  const int t = threadIdx.x;
  const float scale = __expf(-*gmaxPtr);
  if (t < 64) {
    float s = 0.f;
    #pragma unroll 4
    for (int c = 0; c < CPB; ++c)
      s += vsPart[(b * CPB + c) * 64 + t];
    vsumL[t] = s;
  }
  __syncthreads();
  const int o = seg * 256 + t;
  float s = 0.f;
  #pragma unroll 4
  for (int c = 0; c < CPB; ++c)
    s += kvPart[((size_t)(b * CPB + c)) * 2048 + o];
  kvF[b * 2048 + o] = RATIO * (scale * s + EPSK * vsumL[o & 63]);
  if (seg == 0 && t < 32) {
    float ks = 0.f;
    #pragma unroll 4
    for (int c = 0; c < CPB; ++c)
      ks += ksPart[(b * CPB + c) * 32 + t];
    ksF[b * 32 + t] = RATIO * (scale * ks + EPSK * (float)NN);
  }
}

// ---------------- K2c: kvF -> kv B-fragments --------------------------------
__global__ __launch_bounds__(256) void k2c_frag(
    const float* __restrict__ kvF,
    uint4* __restrict__ kfH, uint4* __restrict__ kfL)
{
  __shared__ float kvL[2048];
  const int b = blockIdx.x, t = threadIdx.x;
  #pragma unroll
  for (int ii = 0; ii < 8; ++ii)
    kvL[t + 256*ii] = kvF[b*2048 + t + 256*ii];
  __syncthreads();
  const int l = t & 63, dt = t >> 6;
  const int lr = l & 15, lg = l >> 4;
  float f[8];
  #pragma unroll
  for (int j = 0; j < 8; ++j)
    f[j] = kvL[(lg*8 + j)*64 + dt*16 + lr];
  FragU hi, lo; cvt8(f, hi, lo);
  kfH[(b*4 + dt)*64 + l] = hi.u;
  kfL[(b*4 + dt)*64 + l] = lo.u;
}

// ---------------- K3: dash MFMA -> softmax -> num MFMA (barrier-free) -------
__global__ __launch_bounds__(256, 4) void k3_out(
    const float* __restrict__ q,
    const uint4* __restrict__ pfH, const uint4* __restrict__ pfL,
    const uint4* __restrict__ kfH, const uint4* __restrict__ kfL,
    const float* __restrict__ ksF, float* __restrict__ out)
{
  __shared__ float dashL[256][36];   // fp32 dash; reused per-row as packed pstar
  __shared__ float ssqL[256][4];
  const int t = threadIdx.x;
  const int w = t >> 6, l = t & 63;
  const int lr = l & 15, lg = l >> 4;
  const int b = blockIdx.x >> 5;
  const size_t rowBase = (size_t)blockIdx.x * 256;
  const int wrb = w * 64;

  FragU pbH[2][2], pbL[2][2];
  #pragma unroll
  for (int mt = 0; mt < 2; ++mt)
    #pragma unroll
    for (int ks = 0; ks < 2; ++ks) {
      pbH[mt][ks].u = pfH[(mt*2+ks)*64 + l];
      pbL[mt][ks].u = pfL[(mt*2+ks)*64 + l];
    }

  // phase A
  #pragma unroll
  for (int rt = 0; rt < 4; ++rt) {
    const int rrow = wrb + rt*16 + lr;
    f32x4 acc0 = {0.f,0.f,0.f,0.f}, acc1 = {0.f,0.f,0.f,0.f};
    float sq = 0.f;
    #pragma unroll
    for (int ks = 0; ks < 2; ++ks) {
      const float4* src = (const float4*)(q + (rowBase + rrow)*DD + ks*32 + lg*8);
      float4 a0 = src[0], a1 = src[1];
      float qv[8] = {a0.x,a0.y,a0.z,a0.w, a1.x,a1.y,a1.z,a1.w};
      #pragma unroll
      for (int j = 0; j < 8; ++j) sq += qv[j]*qv[j];
      FragU aH, aL; cvt8(qv, aH, aL);
      acc0 = MFMA(aL.s, pbH[0][ks].s, acc0);
      acc0 = MFMA(aH.s, pbL[0][ks].s, acc0);
      acc0 = MFMA(aH.s, pbH[0][ks].s, acc0);
      acc1 = MFMA(aL.s, pbH[1][ks].s, acc1);
      acc1 = MFMA(aH.s, pbL[1][ks].s, acc1);
      acc1 = MFMA(aH.s, pbH[1][ks].s, acc1);
    }
    ssqL[rrow][lg] = sq;
    #pragma unroll
    for (int reg = 0; reg < 4; ++reg) {
      dashL[wrb + rt*16 + lg*4 + reg][lr]      = acc0[reg];
      dashL[wrb + rt*16 + lg*4 + reg][16 + lr] = acc1[reg];
    }
  }

  // softmax phase: thread t owns row t (same wave as its stripe: no barrier)
  {
    float dv[32];
    const float4* dr = (const float4*)&dashL[t][0];
    #pragma unroll
    for (int i = 0; i < 8; ++i) {
      float4 v4 = dr[i];
      dv[4*i]=v4.x; dv[4*i+1]=v4.y; dv[4*i+2]=v4.z; dv[4*i+3]=v4.w;
    }
    const float ssq = ssqL[t][0]+ssqL[t][1]+ssqL[t][2]+ssqL[t][3];
    float mx = -3.4e38f;
    #pragma unroll
    for (int m = 0; m < MM; ++m) { dv[m] *= NORMC; mx = fmaxf(mx, dv[m]); }
    const float sub = DIAGC * ssq + mx;
    const float* __restrict__ ksb = ksF + b * 32;
    float den = 0.f;
    #pragma unroll
    for (int m = 0; m < MM; ++m) {
      dv[m] = RATIO * (__expf(dv[m] - sub) + EPSK);
      den = fmaf(dv[m], ksb[m], den);
    }
    const float inv = 1.0f / den;
    unsigned hiw[16], low[16];
    #pragma unroll
    for (int u = 0; u < 16; ++u) {
      const float x0 = dv[2*u] * inv, x1 = dv[2*u+1] * inv;
      const unsigned h0 = bf16r(x0);
      const unsigned l0 = bf16r(x0 - __uint_as_float(h0 << 16));
      const unsigned h1 = bf16r(x1);
      const unsigned l1 = bf16r(x1 - __uint_as_float(h1 << 16));
      hiw[u] = h0 | (h1 << 16);
      low[u] = l0 | (l1 << 16);
    }
    uint4* pr = (uint4*)&dashL[t][0];   // overwrite own row only
    pr[0] = make_uint4(hiw[0],hiw[1],hiw[2],hiw[3]);
    pr[1] = make_uint4(hiw[4],hiw[5],hiw[6],hiw[7]);
    pr[2] = make_uint4(hiw[8],hiw[9],hiw[10],hiw[11]);
    pr[3] = make_uint4(hiw[12],hiw[13],hiw[14],hiw[15]);
    pr[4] = make_uint4(low[0],low[1],low[2],low[3]);
    pr[5] = make_uint4(low[4],low[5],low[6],low[7]);
    pr[6] = make_uint4(low[8],low[9],low[10],low[11]);
    pr[7] = make_uint4(low[12],low[13],low[14],low[15]);
  }

  // phase B: out = pstar · kv (K=32, one k-step, 3 comp terms)
  FragU kbH[4], kbL[4];
  #pragma unroll
  for (int dt = 0; dt < 4; ++dt) {
    kbH[dt].u = kfH[(b*4 + dt)*64 + l];
    kbL[dt].u = kfL[(b*4 + dt)*64 + l];
  }
  #pragma unroll
  for (int rt = 0; rt < 4; ++rt) {
    const uint4* pr = (const uint4*)&dashL[wrb + rt*16 + lr][0];
    FragU aH, aL;
    aH.u = pr[lg];
    aL.u = pr[4 + lg];
    #pragma unroll
    for (int dt = 0; dt < 4; ++dt) {
      f32x4 o = {0.f,0.f,0.f,0.f};
      o = MFMA(aL.s, kbH[dt].s, o);
      o = MFMA(aH.s, kbL[dt].s, o);
      o = MFMA(aH.s, kbH[dt].s, o);
      float* ob = out + (rowBase + wrb + rt*16 + lg*4)*DD + dt*16 + lr;
      ob[0]      = o[0];
      ob[DD]     = o[1];
      ob[2*DD]   = o[2];
      ob[3*DD]   = o[3];
    }
  }
}

// ---------------- host ------------------------------------------------------
extern "C" void kernel_launch(void* const* d_in, const int* in_sizes, int n_in,
                              void* d_out, int out_size, void* d_ws, size_t ws_size,
                              hipStream_t stream) {
  const float* q    = (const float*)d_in[0];
  const float* k    = (const float*)d_in[1];
  const float* v    = (const float*)d_in[2];
  const float* proj = (const float*)d_in[3];
  float* out = (float*)d_out;
  float* ws  = (float*)d_ws;

  float*    partialMax = ws;                       // 2048
  float*    gmax       = ws + 2048;                // (pad to 4096)
  float*    kvPart     = ws + 4096;                // 2048*2048
  float*    ksPart     = kvPart + 4194304;         // 2048*32
  float*    vsPart     = ksPart + 65536;           // 2048*64
  float*    ksF        = vsPart + 131072;          // 64*32 (pad 2048)
  float*    kvF        = ksF + 2048;               // 64*2048
  unsigned* pfH        = (unsigned*)(kvF + 131072);// 4*64 uint4 = 1024 words
  unsigned* pfL        = pfH + 1024;               // 1024
  unsigned* kfH        = pfL + 1024;               // 64*4*64 uint4 = 65536 words
  unsigned* kfL        = kfH + 65536;              // 65536

  kfrag_proj<<<1, 256, 0, stream>>>(proj, (uint4*)pfH, (uint4*)pfL);
  k12_kv<<<K12_BLOCKS, 512, 0, stream>>>(k, v, (uint4*)pfH, (uint4*)pfL,
                                         kvPart, ksPart, vsPart, partialMax);
  k1b_reduce_max<<<1, 256, 0, stream>>>(partialMax, gmax);
  k2b_sum<<<BH*8, 256, 0, stream>>>(kvPart, ksPart, vsPart, gmax, kvF, ksF);
  k2c_frag<<<BH, 256, 0, stream>>>(kvF, (uint4*)kfH, (uint4*)kfL);
  k3_out<<<NROWS / 256, 256, 0, stream>>>(q, (uint4*)pfH, (uint4*)pfL,
                                          (uint4*)kfH, (uint4*)kfL, ksF, out);
}

// Round 22
// 152.623 us; speedup vs baseline: 1.1048x; 1.0118x over previous
//
#include <hip/hip_runtime.h>
#include <math.h>

#define BH 64
#define NN 8192
#define DD 64
#define MM 32

#define NROWS (BH*NN)            // 524288
#define NORMC 0.35355339059327379f   // 64^-0.25
#define RATIO 0.17677669529663689f   // 32^-0.5
#define EPSK  1e-4f
#define DIAGC 0.0625f                // 0.5 * 64^-0.5

#define CPB 32                   // chunks per batch
#define CHUNK 256                // rows per chunk (8 waves x 32 rows)
#define K12_BLOCKS (BH*CPB)      // 2048 blocks x 512 threads

typedef __attribute__((ext_vector_type(8))) short short8;
typedef __attribute__((ext_vector_type(4))) float f32x4;

union FragU { uint4 u; short8 s; };

// round-to-nearest-even fp32 -> bf16 (bits in low 16)
__device__ __forceinline__ unsigned bf16r(float x) {
  unsigned u = __float_as_uint(x);
  return (u + 0x7fffu + ((u >> 16) & 1u)) >> 16;
}
// 8 fp32 -> hi/lo bf16x8 fragments (split: x = hi + lo)
__device__ __forceinline__ void cvt8(const float* f, FragU& hi, FragU& lo) {
  unsigned h[8], lw[8];
  #pragma unroll
  for (int j = 0; j < 8; ++j) {
    h[j] = bf16r(f[j]);
    lw[j] = bf16r(f[j] - __uint_as_float(h[j] << 16));
  }
  hi.u = make_uint4(h[0]|(h[1]<<16),  h[2]|(h[3]<<16),  h[4]|(h[5]<<16),  h[6]|(h[7]<<16));
  lo.u = make_uint4(lw[0]|(lw[1]<<16), lw[2]|(lw[3]<<16), lw[4]|(lw[5]<<16), lw[6]|(lw[7]<<16));
}

#define MFMA(a,b,c) __builtin_amdgcn_mfma_f32_16x16x32_bf16((a),(b),(c),0,0,0)

__device__ __forceinline__ float wave_max(float v) {
  #pragma unroll
  for (int off = 32; off > 0; off >>= 1)
    v = fmaxf(v, __shfl_down(v, off, 64));
  return v;
}

// ---------------- proj fragments: hi/lo bf16x8 per (mt,ks,lane) -------------
__global__ void kfrag_proj(const float* __restrict__ proj,
                           uint4* __restrict__ pfH, uint4* __restrict__ pfL)
{
  const int t = threadIdx.x;
  const int l = t & 63, g = t >> 6;          // g = mt*2 + ks
  const int mt = g >> 1, ks = g & 1;
  const int lr = l & 15, lg = l >> 4;
  float f[8];
  #pragma unroll
  for (int j = 0; j < 8; ++j)
    f[j] = proj[(mt*16 + lr)*DD + ks*32 + lg*8 + j];
  FragU hi, lo; cvt8(f, hi, lo);
  pfH[g*64 + l] = hi.u;
  pfL[g*64 + l] = lo.u;
}

// ---------------- K12: FUSED — dash MFMA -> E' (LDS bf16) -> kv MFMA --------
// R22 = R21 structure (8-wave blocks, 1-nb waves, grid 2048) with PERSISTENT
// proj fragments (like k3): the R15 "laundered" per-ks VMEM reloads were a
// legacy fix for the fat 2-nb body's spill; the lean 1-nb body is VGPR 48
// (+32 AGPR = 80) so persistent frags (+32) fit the (512,4) 128-reg budget.
// Removes 32 latency-bearing VMEM ops from each wave's phase-A critical path.
__global__ __launch_bounds__(512, 4) void k12_kv(
    const float* __restrict__ k, const float* __restrict__ v,
    const uint4* __restrict__ pfH, const uint4* __restrict__ pfL,
    float* __restrict__ kvPart, float* __restrict__ ksPart,
    float* __restrict__ vsPart, float* __restrict__ partialMax)
{
  __shared__ float red[10240];     // 40960 B: 8x5KB staging, then reductions
  const int t = threadIdx.x;       // 0..511
  const int w = t >> 6, l = t & 63;
  const int lr = l & 15, lg = l >> 4;
  const int blk = blockIdx.x;
  const int b = blk >> 5, c = blk & (CPB - 1);
  const size_t nrow0 = (size_t)b * NN + (size_t)c * CHUNK + (size_t)w * 32;

  ushort* eh = (ushort*)red + w * 2560;   // [32 m][40] hi  (2560B/wave)
  ushort* el = eh + 1280;                 // [32 m][40] lo

  FragU pbH[2][2], pbL[2][2];      // persistent proj fragments (as in k3)
  #pragma unroll
  for (int mt = 0; mt < 2; ++mt)
    #pragma unroll
    for (int ks = 0; ks < 2; ++ks) {
      pbH[mt][ks].u = pfH[(mt*2+ks)*64 + l];
      pbL[mt][ks].u = pfL[(mt*2+ks)*64 + l];
    }

  f32x4 accK[2][4];
  #pragma unroll
  for (int mt = 0; mt < 2; ++mt)
    #pragma unroll
    for (int dt = 0; dt < 4; ++dt)
      accK[mt][dt] = (f32x4){0.f, 0.f, 0.f, 0.f};
  float ksacc0 = 0.f, ksacc1 = 0.f;
  float vsum[4] = {0.f, 0.f, 0.f, 0.f};
  float tmax = -3.4e38f;

  // ---- phase A: E' for this wave's 32 rows (MFMA dash), staged to LDS
  #pragma unroll
  for (int rt = 0; rt < 2; ++rt) {
    float sq = 0.f;
    f32x4 a0 = {0.f,0.f,0.f,0.f}, a1 = {0.f,0.f,0.f,0.f};
    #pragma unroll
    for (int ks = 0; ks < 2; ++ks) {
      const float4* src = (const float4*)(k + (nrow0 + rt*16 + lr)*DD + ks*32 + lg*8);
      float4 x0 = src[0], x1 = src[1];
      float qv[8] = {x0.x,x0.y,x0.z,x0.w, x1.x,x1.y,x1.z,x1.w};
      #pragma unroll
      for (int j = 0; j < 8; ++j) sq += qv[j]*qv[j];
      FragU aH, aL; cvt8(qv, aH, aL);     // live only inside this ks

      a0 = MFMA(aL.s, pbH[0][ks].s, a0);
      a0 = MFMA(aH.s, pbL[0][ks].s, a0);
      a0 = MFMA(aH.s, pbH[0][ks].s, a0);
      a1 = MFMA(aL.s, pbH[1][ks].s, a1);
      a1 = MFMA(aH.s, pbL[1][ks].s, a1);
      a1 = MFMA(aH.s, pbH[1][ks].s, a1);
    }
    sq += __shfl_xor(sq, 16, 64);
    sq += __shfl_xor(sq, 32, 64);
    unsigned h0w[4], l0w[4], h1w[4], l1w[4];
    #pragma unroll
    for (int reg = 0; reg < 4; ++reg) {
      const float diag = DIAGC * __shfl(sq, lg*4 + reg, 64);
      const float d0 = a0[reg] * NORMC;
      const float d1 = a1[reg] * NORMC;
      tmax = fmaxf(tmax, fmaxf(d0, d1));
      const float e0 = __expf(d0 - diag);
      const float e1 = __expf(d1 - diag);
      ksacc0 += e0;                      // col m = lr
      ksacc1 += e1;                      // col m = lr+16
      h0w[reg] = bf16r(e0);
      l0w[reg] = bf16r(e0 - __uint_as_float(h0w[reg] << 16));
      h1w[reg] = bf16r(e1);
      l1w[reg] = bf16r(e1 - __uint_as_float(h1w[reg] << 16));
    }
    const int nloc = rt*16 + lg*4;       // 4 consecutive ushorts, 4B-aligned
    *(unsigned*)(eh + lr*40      + nloc)     = h0w[0] | (h0w[1] << 16);
    *(unsigned*)(eh + lr*40      + nloc + 2) = h0w[2] | (h0w[3] << 16);
    *(unsigned*)(el + lr*40      + nloc)     = l0w[0] | (l0w[1] << 16);
    *(unsigned*)(el + lr*40      + nloc + 2) = l0w[2] | (l0w[3] << 16);
    *(unsigned*)(eh + (lr+16)*40 + nloc)     = h1w[0] | (h1w[1] << 16);
    *(unsigned*)(eh + (lr+16)*40 + nloc + 2) = h1w[2] | (h1w[3] << 16);
    *(unsigned*)(el + (lr+16)*40 + nloc)     = l1w[0] | (l1w[1] << 16);
    *(unsigned*)(el + (lr+16)*40 + nloc + 2) = l1w[2] | (l1w[3] << 16);
  }

  // ---- phase B: kv += E'^T x v via MFMA (A from LDS, B from global)
  #pragma unroll
  for (int dt = 0; dt < 4; ++dt) {
    float vv[8];
    #pragma unroll
    for (int j = 0; j < 8; ++j)
      vv[j] = v[(nrow0 + lg*8 + j)*DD + dt*16 + lr];
    vsum[dt] += vv[0]+vv[1]+vv[2]+vv[3]+vv[4]+vv[5]+vv[6]+vv[7];
    FragU bHv, bLv; cvt8(vv, bHv, bLv);
    #pragma unroll
    for (int mt = 0; mt < 2; ++mt) {
      FragU aHk, aLk;
      aHk.u = *(const uint4*)(eh + (mt*16 + lr)*40 + lg*8);
      aLk.u = *(const uint4*)(el + (mt*16 + lr)*40 + lg*8);
      accK[mt][dt] = MFMA(aLk.s, bHv.s, accK[mt][dt]);
      accK[mt][dt] = MFMA(aHk.s, bLv.s, accK[mt][dt]);
      accK[mt][dt] = MFMA(aHk.s, bHv.s, accK[mt][dt]);
    }
  }

  // ---- epilogue: wave reductions, then two-stage cross-wave reduction
  tmax = wave_max(tmax);
  ksacc0 += __shfl_xor(ksacc0, 16, 64);
  ksacc0 += __shfl_xor(ksacc0, 32, 64);
  ksacc1 += __shfl_xor(ksacc1, 16, 64);
  ksacc1 += __shfl_xor(ksacc1, 32, 64);
  #pragma unroll
  for (int dt = 0; dt < 4; ++dt) {
    vsum[dt] += __shfl_xor(vsum[dt], 16, 64);
    vsum[dt] += __shfl_xor(vsum[dt], 32, 64);
  }
  __syncthreads();                 // all staging reads done; red reusable
  if (w < 4) {
    #pragma unroll
    for (int mt = 0; mt < 2; ++mt)
      #pragma unroll
      for (int dt = 0; dt < 4; ++dt)
        #pragma unroll
        for (int reg = 0; reg < 4; ++reg)
          red[((mt*16 + lg*4 + reg)*64 + dt*16 + lr)*4 + w] = accK[mt][dt][reg];
  }
  if (l == 0) red[8192 + w] = tmax;
  __syncthreads();
  if (w >= 4) {
    #pragma unroll
    for (int mt = 0; mt < 2; ++mt)
      #pragma unroll
      for (int dt = 0; dt < 4; ++dt)
        #pragma unroll
        for (int reg = 0; reg < 4; ++reg)
          red[((mt*16 + lg*4 + reg)*64 + dt*16 + lr)*4 + (w-4)] += accK[mt][dt][reg];
  }
  __syncthreads();
  if (t == 0) {
    float mx = red[8192];
    #pragma unroll
    for (int i = 1; i < 8; ++i) mx = fmaxf(mx, red[8192+i]);
    partialMax[blk] = mx;
  }
  #pragma unroll
  for (int ii = 0; ii < 4; ++ii) {
    const int o = t + 512 * ii;
    const float4 r4 = *(const float4*)&red[o*4];
    kvPart[(size_t)blk * 2048 + o] = r4.x + r4.y + r4.z + r4.w;
  }
  __syncthreads();
  if (l < 16) {
    red[w*32 + lr]        = ksacc0;
    red[w*32 + 16 + lr]   = ksacc1;
    #pragma unroll
    for (int dt = 0; dt < 4; ++dt)
      red[256 + w*64 + dt*16 + lr] = vsum[dt];
  }
  __syncthreads();
  if (t < 32) {
    float s = 0.f;
    #pragma unroll
    for (int ww = 0; ww < 8; ++ww) s += red[ww*32 + t];
    ksPart[blk*32 + t] = s;
  }
  if (t < 64) {
    float s = 0.f;
    #pragma unroll
    for (int ww = 0; ww < 8; ++ww) s += red[256 + ww*64 + t];
    vsPart[blk*64 + t] = s;
  }
}

// ---------------- K1b: reduce partial maxes (2048) -> global max ------------
__global__ __launch_bounds__(256) void k1b_reduce_max(
    const float* __restrict__ partialMax, float* __restrict__ gmax)
{
  const int t = threadIdx.x;
  float mx = -3.4e38f;
  for (int i = t; i < K12_BLOCKS; i += 256) mx = fmaxf(mx, partialMax[i]);
  mx = wave_max(mx);
  __shared__ float wmaxs[4];
  if ((t & 63) == 0) wmaxs[t >> 6] = mx;
  __syncthreads();
  if (t == 0)
    *gmax = fmaxf(fmaxf(wmaxs[0], wmaxs[1]), fmaxf(wmaxs[2], wmaxs[3]));
}

// ---------------- K2b_sum: PARALLEL chunk reduction -> kvF, ksF -------------
__global__ __launch_bounds__(256) void k2b_sum(
    const float* __restrict__ kvPart, const float* __restrict__ ksPart,
    const float* __restrict__ vsPart, const float* __restrict__ gmaxPtr,
    float* __restrict__ kvF, float* __restrict__ ksF)
{
  __shared__ float vsumL[64];
  const int blk = blockIdx.x;
  const int b = blk >> 3, seg = blk & 7;
  const int t = threadIdx.x;
  const float scale = __expf(-*gmaxPtr);
  if (t < 64) {
    float s = 0.f;
    #pragma unroll 4
    for (int c = 0; c < CPB; ++c)
      s += vsPart[(b * CPB + c) * 64 + t];
    vsumL[t] = s;
  }
  __syncthreads();
  const int o = seg * 256 + t;
  float s = 0.f;
  #pragma unroll 4
  for (int c = 0; c < CPB; ++c)
    s += kvPart[((size_t)(b * CPB + c)) * 2048 + o];
  kvF[b * 2048 + o] = RATIO * (scale * s + EPSK * vsumL[o & 63]);
  if (seg == 0 && t < 32) {
    float ks = 0.f;
    #pragma unroll 4
    for (int c = 0; c < CPB; ++c)
      ks += ksPart[(b * CPB + c) * 32 + t];
    ksF[b * 32 + t] = RATIO * (scale * ks + EPSK * (float)NN);
  }
}

// ---------------- K2c: kvF -> kv B-fragments --------------------------------
__global__ __launch_bounds__(256) void k2c_frag(
    const float* __restrict__ kvF,
    uint4* __restrict__ kfH, uint4* __restrict__ kfL)
{
  __shared__ float kvL[2048];
  const int b = blockIdx.x, t = threadIdx.x;
  #pragma unroll
  for (int ii = 0; ii < 8; ++ii)
    kvL[t + 256*ii] = kvF[b*2048 + t + 256*ii];
  __syncthreads();
  const int l = t & 63, dt = t >> 6;
  const int lr = l & 15, lg = l >> 4;
  float f[8];
  #pragma unroll
  for (int j = 0; j < 8; ++j)
    f[j] = kvL[(lg*8 + j)*64 + dt*16 + lr];
  FragU hi, lo; cvt8(f, hi, lo);
  kfH[(b*4 + dt)*64 + l] = hi.u;
  kfL[(b*4 + dt)*64 + l] = lo.u;
}

// ---------------- K3: dash MFMA -> softmax -> num MFMA (barrier-free) -------
__global__ __launch_bounds__(256, 4) void k3_out(
    const float* __restrict__ q,
    const uint4* __restrict__ pfH, const uint4* __restrict__ pfL,
    const uint4* __restrict__ kfH, const uint4* __restrict__ kfL,
    const float* __restrict__ ksF, float* __restrict__ out)
{
  __shared__ float dashL[256][36];   // fp32 dash; reused per-row as packed pstar
  __shared__ float ssqL[256][4];
  const int t = threadIdx.x;
  const int w = t >> 6, l = t & 63;
  const int lr = l & 15, lg = l >> 4;
  const int b = blockIdx.x >> 5;
  const size_t rowBase = (size_t)blockIdx.x * 256;
  const int wrb = w * 64;

  FragU pbH[2][2], pbL[2][2];
  #pragma unroll
  for (int mt = 0; mt < 2; ++mt)
    #pragma unroll
    for (int ks = 0; ks < 2; ++ks) {
      pbH[mt][ks].u = pfH[(mt*2+ks)*64 + l];
      pbL[mt][ks].u = pfL[(mt*2+ks)*64 + l];
    }

  // phase A
  #pragma unroll
  for (int rt = 0; rt < 4; ++rt) {
    const int rrow = wrb + rt*16 + lr;
    f32x4 acc0 = {0.f,0.f,0.f,0.f}, acc1 = {0.f,0.f,0.f,0.f};
    float sq = 0.f;
    #pragma unroll
    for (int ks = 0; ks < 2; ++ks) {
      const float4* src = (const float4*)(q + (rowBase + rrow)*DD + ks*32 + lg*8);
      float4 a0 = src[0], a1 = src[1];
      float qv[8] = {a0.x,a0.y,a0.z,a0.w, a1.x,a1.y,a1.z,a1.w};
      #pragma unroll
      for (int j = 0; j < 8; ++j) sq += qv[j]*qv[j];
      FragU aH, aL; cvt8(qv, aH, aL);
      acc0 = MFMA(aL.s, pbH[0][ks].s, acc0);
      acc0 = MFMA(aH.s, pbL[0][ks].s, acc0);
      acc0 = MFMA(aH.s, pbH[0][ks].s, acc0);
      acc1 = MFMA(aL.s, pbH[1][ks].s, acc1);
      acc1 = MFMA(aH.s, pbL[1][ks].s, acc1);
      acc1 = MFMA(aH.s, pbH[1][ks].s, acc1);
    }
    ssqL[rrow][lg] = sq;
    #pragma unroll
    for (int reg = 0; reg < 4; ++reg) {
      dashL[wrb + rt*16 + lg*4 + reg][lr]      = acc0[reg];
      dashL[wrb + rt*16 + lg*4 + reg][16 + lr] = acc1[reg];
    }
  }

  // softmax phase: thread t owns row t (same wave as its stripe: no barrier)
  {
    float dv[32];
    const float4* dr = (const float4*)&dashL[t][0];
    #pragma unroll
    for (int i = 0; i < 8; ++i) {
      float4 v4 = dr[i];
      dv[4*i]=v4.x; dv[4*i+1]=v4.y; dv[4*i+2]=v4.z; dv[4*i+3]=v4.w;
    }
    const float ssq = ssqL[t][0]+ssqL[t][1]+ssqL[t][2]+ssqL[t][3];
    float mx = -3.4e38f;
    #pragma unroll
    for (int m = 0; m < MM; ++m) { dv[m] *= NORMC; mx = fmaxf(mx, dv[m]); }
    const float sub = DIAGC * ssq + mx;
    const float* __restrict__ ksb = ksF + b * 32;
    float den = 0.f;
    #pragma unroll
    for (int m = 0; m < MM; ++m) {
      dv[m] = RATIO * (__expf(dv[m] - sub) + EPSK);
      den = fmaf(dv[m], ksb[m], den);
    }
    const float inv = 1.0f / den;
    unsigned hiw[16], low[16];
    #pragma unroll
    for (int u = 0; u < 16; ++u) {
      const float x0 = dv[2*u] * inv, x1 = dv[2*u+1] * inv;
      const unsigned h0 = bf16r(x0);
      const unsigned l0 = bf16r(x0 - __uint_as_float(h0 << 16));
      const unsigned h1 = bf16r(x1);
      const unsigned l1 = bf16r(x1 - __uint_as_float(h1 << 16));
      hiw[u] = h0 | (h1 << 16);
      low[u] = l0 | (l1 << 16);
    }
    uint4* pr = (uint4*)&dashL[t][0];   // overwrite own row only
    pr[0] = make_uint4(hiw[0],hiw[1],hiw[2],hiw[3]);
    pr[1] = make_uint4(hiw[4],hiw[5],hiw[6],hiw[7]);
    pr[2] = make_uint4(hiw[8],hiw[9],hiw[10],hiw[11]);
    pr[3] = make_uint4(hiw[12],hiw[13],hiw[14],hiw[15]);
    pr[4] = make_uint4(low[0],low[1],low[2],low[3]);
    pr[5] = make_uint4(low[4],low[5],low[6],low[7]);
    pr[6] = make_uint4(low[8],low[9],low[10],low[11]);
    pr[7] = make_uint4(low[12],low[13],low[14],low[15]);
  }

  // phase B: out = pstar · kv (K=32, one k-step, 3 comp terms)
  FragU kbH[4], kbL[4];
  #pragma unroll
  for (int dt = 0; dt < 4; ++dt) {
    kbH[dt].u = kfH[(b*4 + dt)*64 + l];
    kbL[dt].u = kfL[(b*4 + dt)*64 + l];
  }
  #pragma unroll
  for (int rt = 0; rt < 4; ++rt) {
    const uint4* pr = (const uint4*)&dashL[wrb + rt*16 + lr][0];
    FragU aH, aL;
    aH.u = pr[lg];
    aL.u = pr[4 + lg];
    #pragma unroll
    for (int dt = 0; dt < 4; ++dt) {
      f32x4 o = {0.f,0.f,0.f,0.f};
      o = MFMA(aL.s, kbH[dt].s, o);
      o = MFMA(aH.s, kbL[dt].s, o);
      o = MFMA(aH.s, kbH[dt].s, o);
      float* ob = out + (rowBase + wrb + rt*16 + lg*4)*DD + dt*16 + lr;
      ob[0]      = o[0];
      ob[DD]     = o[1];
      ob[2*DD]   = o[2];
      ob[3*DD]   = o[3];
    }
  }
}

// ---------------- host ------------------------------------------------------
extern "C" void kernel_launch(void* const* d_in, const int* in_sizes, int n_in,
                              void* d_out, int out_size, void* d_ws, size_t ws_size,
                              hipStream_t stream) {
  const float* q    = (const float*)d_in[0];
  const float* k    = (const float*)d_in[1];
  const float* v    = (const float*)d_in[2];
  const float* proj = (const float*)d_in[3];
  float* out = (float*)d_out;
  float* ws  = (float*)d_ws;

  float*    partialMax = ws;                       // 2048
  float*    gmax       = ws + 2048;                // (pad to 4096)
  float*    kvPart     = ws + 4096;                // 2048*2048
  float*    ksPart     = kvPart + 4194304;         // 2048*32
  float*    vsPart     = ksPart + 65536;           // 2048*64
  float*    ksF        = vsPart + 131072;          // 64*32 (pad 2048)
  float*    kvF        = ksF + 2048;               // 64*2048
  unsigned* pfH        = (unsigned*)(kvF + 131072);// 4*64 uint4 = 1024 words
  unsigned* pfL        = pfH + 1024;               // 1024
  unsigned* kfH        = pfL + 1024;               // 64*4*64 uint4 = 65536 words
  unsigned* kfL        = kfH + 65536;              // 65536

  kfrag_proj<<<1, 256, 0, stream>>>(proj, (uint4*)pfH, (uint4*)pfL);
  k12_kv<<<K12_BLOCKS, 512, 0, stream>>>(k, v, (uint4*)pfH, (uint4*)pfL,
                                         kvPart, ksPart, vsPart, partialMax);
  k1b_reduce_max<<<1, 256, 0, stream>>>(partialMax, gmax);
  k2b_sum<<<BH*8, 256, 0, stream>>>(kvPart, ksPart, vsPart, gmax, kvF, ksF);
  k2c_frag<<<BH, 256, 0, stream>>>(kvF, (uint4*)kfH, (uint4*)kfL);
  k3_out<<<NROWS / 256, 256, 0, stream>>>(q, (uint4*)pfH, (uint4*)pfL,
                                          (uint4*)kfH, (uint4*)kfL, ksF, out);
}

// Round 23
// 147.012 us; speedup vs baseline: 1.1469x; 1.0382x over previous
//
#include <hip/hip_runtime.h>
#include <hip/hip_bf16.h>
#include <math.h>

#define BH 64
#define NN 8192
#define DD 64
#define MM 32

#define NROWS (BH*NN)            // 524288
#define NORMC 0.35355339059327379f   // 64^-0.25
#define RATIO 0.17677669529663689f   // 32^-0.5
#define EPSK  1e-4f
#define DIAGC 0.0625f                // 0.5 * 64^-0.5

#define CPB 32                   // chunks per batch
#define CHUNK 256                // rows per chunk (8 waves x 32 rows)
#define K12_BLOCKS (BH*CPB)      // 2048 blocks x 512 threads

typedef __attribute__((ext_vector_type(8))) short short8;
typedef __attribute__((ext_vector_type(4))) float f32x4;

union FragU { uint4 u; short8 s; };

// packed fp32x2 -> bf16x2 (round-nearest-even, HW conversion)
__device__ __forceinline__ unsigned pkbf(float a, float b) {
  union { __hip_bfloat162 b2; unsigned u; } r;
  r.b2 = __float22bfloat162_rn(make_float2(a, b));
  return r.u;
}
// packed lo-residuals given the packed hi word (hi values via bit-mask)
__device__ __forceinline__ unsigned pklo(float a, float b, unsigned h) {
  const float ha = __uint_as_float(h << 16);
  const float hb = __uint_as_float(h & 0xffff0000u);
  return pkbf(a - ha, b - hb);
}
// 8 fp32 -> hi/lo bf16x8 fragments (split: x = hi + lo)
__device__ __forceinline__ void cvt8(const float* f, FragU& hi, FragU& lo) {
  unsigned hw[4], lw[4];
  #pragma unroll
  for (int p = 0; p < 4; ++p) {
    hw[p] = pkbf(f[2*p], f[2*p+1]);
    lw[p] = pklo(f[2*p], f[2*p+1], hw[p]);
  }
  hi.u = make_uint4(hw[0], hw[1], hw[2], hw[3]);
  lo.u = make_uint4(lw[0], lw[1], lw[2], lw[3]);
}

#define MFMA(a,b,c) __builtin_amdgcn_mfma_f32_16x16x32_bf16((a),(b),(c),0,0,0)

__device__ __forceinline__ float wave_max(float v) {
  #pragma unroll
  for (int off = 32; off > 0; off >>= 1)
    v = fmaxf(v, __shfl_down(v, off, 64));
  return v;
}

// ---------------- proj fragments: hi/lo bf16x8 per (mt,ks,lane) -------------
__global__ void kfrag_proj(const float* __restrict__ proj,
                           uint4* __restrict__ pfH, uint4* __restrict__ pfL)
{
  const int t = threadIdx.x;
  const int l = t & 63, g = t >> 6;          // g = mt*2 + ks
  const int mt = g >> 1, ks = g & 1;
  const int lr = l & 15, lg = l >> 4;
  float f[8];
  #pragma unroll
  for (int j = 0; j < 8; ++j)
    f[j] = proj[(mt*16 + lr)*DD + ks*32 + lg*8 + j];
  FragU hi, lo; cvt8(f, hi, lo);
  pfH[g*64 + l] = hi.u;
  pfL[g*64 + l] = lo.u;
}

// ---------------- K12: FUSED — dash MFMA -> E' (LDS bf16) -> kv MFMA --------
// R23 = R22 structure with packed HW bf16 conversions (pkbf/pklo): the
// manual bf16r bit-math made conversion ~900 VALU ops/wave vs 180 cy of
// MFMA — the dominant serial cost. Packed conversions cut it ~2.5x with
// bit-identical rounding (rn).
__global__ __launch_bounds__(512, 4) void k12_kv(
    const float* __restrict__ k, const float* __restrict__ v,
    const uint4* __restrict__ pfH, const uint4* __restrict__ pfL,
    float* __restrict__ kvPart, float* __restrict__ ksPart,
    float* __restrict__ vsPart, float* __restrict__ partialMax)
{
  __shared__ float red[10240];     // 40960 B: 8x5KB staging, then reductions
  const int t = threadIdx.x;       // 0..511
  const int w = t >> 6, l = t & 63;
  const int lr = l & 15, lg = l >> 4;
  const int blk = blockIdx.x;
  const int b = blk >> 5, c = blk & (CPB - 1);
  const size_t nrow0 = (size_t)b * NN + (size_t)c * CHUNK + (size_t)w * 32;

  ushort* eh = (ushort*)red + w * 2560;   // [32 m][40] hi  (2560B/wave)
  ushort* el = eh + 1280;                 // [32 m][40] lo

  FragU pbH[2][2], pbL[2][2];      // persistent proj fragments
  #pragma unroll
  for (int mt = 0; mt < 2; ++mt)
    #pragma unroll
    for (int ks = 0; ks < 2; ++ks) {
      pbH[mt][ks].u = pfH[(mt*2+ks)*64 + l];
      pbL[mt][ks].u = pfL[(mt*2+ks)*64 + l];
    }

  f32x4 accK[2][4];
  #pragma unroll
  for (int mt = 0; mt < 2; ++mt)
    #pragma unroll
    for (int dt = 0; dt < 4; ++dt)
      accK[mt][dt] = (f32x4){0.f, 0.f, 0.f, 0.f};
  float ksacc0 = 0.f, ksacc1 = 0.f;
  float vsum[4] = {0.f, 0.f, 0.f, 0.f};
  float tmax = -3.4e38f;

  // ---- phase A: E' for this wave's 32 rows (MFMA dash), staged to LDS
  #pragma unroll
  for (int rt = 0; rt < 2; ++rt) {
    float sq = 0.f;
    f32x4 a0 = {0.f,0.f,0.f,0.f}, a1 = {0.f,0.f,0.f,0.f};
    #pragma unroll
    for (int ks = 0; ks < 2; ++ks) {
      const float4* src = (const float4*)(k + (nrow0 + rt*16 + lr)*DD + ks*32 + lg*8);
      float4 x0 = src[0], x1 = src[1];
      float qv[8] = {x0.x,x0.y,x0.z,x0.w, x1.x,x1.y,x1.z,x1.w};
      #pragma unroll
      for (int j = 0; j < 8; ++j) sq += qv[j]*qv[j];
      FragU aH, aL; cvt8(qv, aH, aL);     // live only inside this ks

      a0 = MFMA(aL.s, pbH[0][ks].s, a0);
      a0 = MFMA(aH.s, pbL[0][ks].s, a0);
      a0 = MFMA(aH.s, pbH[0][ks].s, a0);
      a1 = MFMA(aL.s, pbH[1][ks].s, a1);
      a1 = MFMA(aH.s, pbL[1][ks].s, a1);
      a1 = MFMA(aH.s, pbH[1][ks].s, a1);
    }
    sq += __shfl_xor(sq, 16, 64);
    sq += __shfl_xor(sq, 32, 64);
    float e0v[4], e1v[4];
    #pragma unroll
    for (int reg = 0; reg < 4; ++reg) {
      const float diag = DIAGC * __shfl(sq, lg*4 + reg, 64);
      const float d0 = a0[reg] * NORMC;
      const float d1 = a1[reg] * NORMC;
      tmax = fmaxf(tmax, fmaxf(d0, d1));
      e0v[reg] = __expf(d0 - diag);
      e1v[reg] = __expf(d1 - diag);
      ksacc0 += e0v[reg];                // col m = lr
      ksacc1 += e1v[reg];                // col m = lr+16
    }
    const int nloc = rt*16 + lg*4;       // 4 consecutive ushorts, 4B-aligned
    const unsigned h00 = pkbf(e0v[0], e0v[1]), h01 = pkbf(e0v[2], e0v[3]);
    const unsigned l00 = pklo(e0v[0], e0v[1], h00), l01 = pklo(e0v[2], e0v[3], h01);
    const unsigned h10 = pkbf(e1v[0], e1v[1]), h11 = pkbf(e1v[2], e1v[3]);
    const unsigned l10 = pklo(e1v[0], e1v[1], h10), l11 = pklo(e1v[2], e1v[3], h11);
    *(unsigned*)(eh + lr*40      + nloc)     = h00;
    *(unsigned*)(eh + lr*40      + nloc + 2) = h01;
    *(unsigned*)(el + lr*40      + nloc)     = l00;
    *(unsigned*)(el + lr*40      + nloc + 2) = l01;
    *(unsigned*)(eh + (lr+16)*40 + nloc)     = h10;
    *(unsigned*)(eh + (lr+16)*40 + nloc + 2) = h11;
    *(unsigned*)(el + (lr+16)*40 + nloc)     = l10;
    *(unsigned*)(el + (lr+16)*40 + nloc + 2) = l11;
  }

  // ---- phase B: kv += E'^T x v via MFMA (A from LDS, B from global)
  #pragma unroll
  for (int dt = 0; dt < 4; ++dt) {
    float vv[8];
    #pragma unroll
    for (int j = 0; j < 8; ++j)
      vv[j] = v[(nrow0 + lg*8 + j)*DD + dt*16 + lr];
    vsum[dt] += vv[0]+vv[1]+vv[2]+vv[3]+vv[4]+vv[5]+vv[6]+vv[7];
    FragU bHv, bLv; cvt8(vv, bHv, bLv);
    #pragma unroll
    for (int mt = 0; mt < 2; ++mt) {
      FragU aHk, aLk;
      aHk.u = *(const uint4*)(eh + (mt*16 + lr)*40 + lg*8);
      aLk.u = *(const uint4*)(el + (mt*16 + lr)*40 + lg*8);
      accK[mt][dt] = MFMA(aLk.s, bHv.s, accK[mt][dt]);
      accK[mt][dt] = MFMA(aHk.s, bLv.s, accK[mt][dt]);
      accK[mt][dt] = MFMA(aHk.s, bHv.s, accK[mt][dt]);
    }
  }

  // ---- epilogue: wave reductions, then two-stage cross-wave reduction
  tmax = wave_max(tmax);
  ksacc0 += __shfl_xor(ksacc0, 16, 64);
  ksacc0 += __shfl_xor(ksacc0, 32, 64);
  ksacc1 += __shfl_xor(ksacc1, 16, 64);
  ksacc1 += __shfl_xor(ksacc1, 32, 64);
  #pragma unroll
  for (int dt = 0; dt < 4; ++dt) {
    vsum[dt] += __shfl_xor(vsum[dt], 16, 64);
    vsum[dt] += __shfl_xor(vsum[dt], 32, 64);
  }
  __syncthreads();                 // all staging reads done; red reusable
  if (w < 4) {
    #pragma unroll
    for (int mt = 0; mt < 2; ++mt)
      #pragma unroll
      for (int dt = 0; dt < 4; ++dt)
        #pragma unroll
        for (int reg = 0; reg < 4; ++reg)
          red[((mt*16 + lg*4 + reg)*64 + dt*16 + lr)*4 + w] = accK[mt][dt][reg];
  }
  if (l == 0) red[8192 + w] = tmax;
  __syncthreads();
  if (w >= 4) {
    #pragma unroll
    for (int mt = 0; mt < 2; ++mt)
      #pragma unroll
      for (int dt = 0; dt < 4; ++dt)
        #pragma unroll
        for (int reg = 0; reg < 4; ++reg)
          red[((mt*16 + lg*4 + reg)*64 + dt*16 + lr)*4 + (w-4)] += accK[mt][dt][reg];
  }
  __syncthreads();
  if (t == 0) {
    float mx = red[8192];
    #pragma unroll
    for (int i = 1; i < 8; ++i) mx = fmaxf(mx, red[8192+i]);
    partialMax[blk] = mx;
  }
  #pragma unroll
  for (int ii = 0; ii < 4; ++ii) {
    const int o = t + 512 * ii;
    const float4 r4 = *(const float4*)&red[o*4];
    kvPart[(size_t)blk * 2048 + o] = r4.x + r4.y + r4.z + r4.w;
  }
  __syncthreads();
  if (l < 16) {
    red[w*32 + lr]        = ksacc0;
    red[w*32 + 16 + lr]   = ksacc1;
    #pragma unroll
    for (int dt = 0; dt < 4; ++dt)
      red[256 + w*64 + dt*16 + lr] = vsum[dt];
  }
  __syncthreads();
  if (t < 32) {
    float s = 0.f;
    #pragma unroll
    for (int ww = 0; ww < 8; ++ww) s += red[ww*32 + t];
    ksPart[blk*32 + t] = s;
  }
  if (t < 64) {
    float s = 0.f;
    #pragma unroll
    for (int ww = 0; ww < 8; ++ww) s += red[256 + ww*64 + t];
    vsPart[blk*64 + t] = s;
  }
}

// ---------------- K2b_sum: gmax (redundant per block) + parallel reduction --
// k1b merged in: every block computes the identical gmax from the 2048
// partials (fixed order, L2-hot) -> one fewer dispatch.
__global__ __launch_bounds__(256) void k2b_sum(
    const float* __restrict__ partialMax,
    const float* __restrict__ kvPart, const float* __restrict__ ksPart,
    const float* __restrict__ vsPart,
    float* __restrict__ kvF, float* __restrict__ ksF)
{
  __shared__ float vsumL[64];
  __shared__ float wred[4];
  const int blk = blockIdx.x;
  const int b = blk >> 3, seg = blk & 7;
  const int t = threadIdx.x;
  float mx = -3.4e38f;
  for (int i = t; i < K12_BLOCKS; i += 256) mx = fmaxf(mx, partialMax[i]);
  mx = wave_max(mx);
  if ((t & 63) == 0) wred[t >> 6] = mx;
  if (t < 64) {
    float s = 0.f;
    #pragma unroll 4
    for (int c = 0; c < CPB; ++c)
      s += vsPart[(b * CPB + c) * 64 + t];
    vsumL[t] = s;
  }
  __syncthreads();
  const float scale =
      __expf(-fmaxf(fmaxf(wred[0], wred[1]), fmaxf(wred[2], wred[3])));
  const int o = seg * 256 + t;
  float s = 0.f;
  #pragma unroll 4
  for (int c = 0; c < CPB; ++c)
    s += kvPart[((size_t)(b * CPB + c)) * 2048 + o];
  kvF[b * 2048 + o] = RATIO * (scale * s + EPSK * vsumL[o & 63]);
  if (seg == 0 && t < 32) {
    float ks = 0.f;
    #pragma unroll 4
    for (int c = 0; c < CPB; ++c)
      ks += ksPart[(b * CPB + c) * 32 + t];
    ksF[b * 32 + t] = RATIO * (scale * ks + EPSK * (float)NN);
  }
}

// ---------------- K2c: kvF -> kv B-fragments --------------------------------
__global__ __launch_bounds__(256) void k2c_frag(
    const float* __restrict__ kvF,
    uint4* __restrict__ kfH, uint4* __restrict__ kfL)
{
  __shared__ float kvL[2048];
  const int b = blockIdx.x, t = threadIdx.x;
  #pragma unroll
  for (int ii = 0; ii < 8; ++ii)
    kvL[t + 256*ii] = kvF[b*2048 + t + 256*ii];
  __syncthreads();
  const int l = t & 63, dt = t >> 6;
  const int lr = l & 15, lg = l >> 4;
  float f[8];
  #pragma unroll
  for (int j = 0; j < 8; ++j)
    f[j] = kvL[(lg*8 + j)*64 + dt*16 + lr];
  FragU hi, lo; cvt8(f, hi, lo);
  kfH[(b*4 + dt)*64 + l] = hi.u;
  kfL[(b*4 + dt)*64 + l] = lo.u;
}

// ---------------- K3: dash MFMA -> softmax -> num MFMA (barrier-free) -------
__global__ __launch_bounds__(256, 4) void k3_out(
    const float* __restrict__ q,
    const uint4* __restrict__ pfH, const uint4* __restrict__ pfL,
    const uint4* __restrict__ kfH, const uint4* __restrict__ kfL,
    const float* __restrict__ ksF, float* __restrict__ out)
{
  __shared__ float dashL[256][36];   // fp32 dash; reused per-row as packed pstar
  __shared__ float ssqL[256][4];
  const int t = threadIdx.x;
  const int w = t >> 6, l = t & 63;
  const int lr = l & 15, lg = l >> 4;
  const int b = blockIdx.x >> 5;
  const size_t rowBase = (size_t)blockIdx.x * 256;
  const int wrb = w * 64;

  FragU pbH[2][2], pbL[2][2];
  #pragma unroll
  for (int mt = 0; mt < 2; ++mt)
    #pragma unroll
    for (int ks = 0; ks < 2; ++ks) {
      pbH[mt][ks].u = pfH[(mt*2+ks)*64 + l];
      pbL[mt][ks].u = pfL[(mt*2+ks)*64 + l];
    }

  // phase A
  #pragma unroll
  for (int rt = 0; rt < 4; ++rt) {
    const int rrow = wrb + rt*16 + lr;
    f32x4 acc0 = {0.f,0.f,0.f,0.f}, acc1 = {0.f,0.f,0.f,0.f};
    float sq = 0.f;
    #pragma unroll
    for (int ks = 0; ks < 2; ++ks) {
      const float4* src = (const float4*)(q + (rowBase + rrow)*DD + ks*32 + lg*8);
      float4 a0 = src[0], a1 = src[1];
      float qv[8] = {a0.x,a0.y,a0.z,a0.w, a1.x,a1.y,a1.z,a1.w};
      #pragma unroll
      for (int j = 0; j < 8; ++j) sq += qv[j]*qv[j];
      FragU aH, aL; cvt8(qv, aH, aL);
      acc0 = MFMA(aL.s, pbH[0][ks].s, acc0);
      acc0 = MFMA(aH.s, pbL[0][ks].s, acc0);
      acc0 = MFMA(aH.s, pbH[0][ks].s, acc0);
      acc1 = MFMA(aL.s, pbH[1][ks].s, acc1);
      acc1 = MFMA(aH.s, pbL[1][ks].s, acc1);
      acc1 = MFMA(aH.s, pbH[1][ks].s, acc1);
    }
    ssqL[rrow][lg] = sq;
    #pragma unroll
    for (int reg = 0; reg < 4; ++reg) {
      dashL[wrb + rt*16 + lg*4 + reg][lr]      = acc0[reg];
      dashL[wrb + rt*16 + lg*4 + reg][16 + lr] = acc1[reg];
    }
  }

  // softmax phase: thread t owns row t (same wave as its stripe: no barrier)
  {
    float dv[32];
    const float4* dr = (const float4*)&dashL[t][0];
    #pragma unroll
    for (int i = 0; i < 8; ++i) {
      float4 v4 = dr[i];
      dv[4*i]=v4.x; dv[4*i+1]=v4.y; dv[4*i+2]=v4.z; dv[4*i+3]=v4.w;
    }
    const float ssq = ssqL[t][0]+ssqL[t][1]+ssqL[t][2]+ssqL[t][3];
    float mx = -3.4e38f;
    #pragma unroll
    for (int m = 0; m < MM; ++m) { dv[m] *= NORMC; mx = fmaxf(mx, dv[m]); }
    const float sub = DIAGC * ssq + mx;
    const float* __restrict__ ksb = ksF + b * 32;
    float den = 0.f;
    #pragma unroll
    for (int m = 0; m < MM; ++m) {
      dv[m] = RATIO * (__expf(dv[m] - sub) + EPSK);
      den = fmaf(dv[m], ksb[m], den);
    }
    const float inv = 1.0f / den;
    unsigned hiw[16], low[16];
    #pragma unroll
    for (int u = 0; u < 16; ++u) {
      const float x0 = dv[2*u] * inv, x1 = dv[2*u+1] * inv;
      hiw[u] = pkbf(x0, x1);
      low[u] = pklo(x0, x1, hiw[u]);
    }
    uint4* pr = (uint4*)&dashL[t][0];   // overwrite own row only
    pr[0] = make_uint4(hiw[0],hiw[1],hiw[2],hiw[3]);
    pr[1] = make_uint4(hiw[4],hiw[5],hiw[6],hiw[7]);
    pr[2] = make_uint4(hiw[8],hiw[9],hiw[10],hiw[11]);
    pr[3] = make_uint4(hiw[12],hiw[13],hiw[14],hiw[15]);
    pr[4] = make_uint4(low[0],low[1],low[2],low[3]);
    pr[5] = make_uint4(low[4],low[5],low[6],low[7]);
    pr[6] = make_uint4(low[8],low[9],low[10],low[11]);
    pr[7] = make_uint4(low[12],low[13],low[14],low[15]);
  }

  // phase B: out = pstar · kv (K=32, one k-step, 3 comp terms)
  FragU kbH[4], kbL[4];
  #pragma unroll
  for (int dt = 0; dt < 4; ++dt) {
    kbH[dt].u = kfH[(b*4 + dt)*64 + l];
    kbL[dt].u = kfL[(b*4 + dt)*64 + l];
  }
  #pragma unroll
  for (int rt = 0; rt < 4; ++rt) {
    const uint4* pr = (const uint4*)&dashL[wrb + rt*16 + lr][0];
    FragU aH, aL;
    aH.u = pr[lg];
    aL.u = pr[4 + lg];
    #pragma unroll
    for (int dt = 0; dt < 4; ++dt) {
      f32x4 o = {0.f,0.f,0.f,0.f};
      o = MFMA(aL.s, kbH[dt].s, o);
      o = MFMA(aH.s, kbL[dt].s, o);
      o = MFMA(aH.s, kbH[dt].s, o);
      float* ob = out + (rowBase + wrb + rt*16 + lg*4)*DD + dt*16 + lr;
      ob[0]      = o[0];
      ob[DD]     = o[1];
      ob[2*DD]   = o[2];
      ob[3*DD]   = o[3];
    }
  }
}

// ---------------- host ------------------------------------------------------
extern "C" void kernel_launch(void* const* d_in, const int* in_sizes, int n_in,
                              void* d_out, int out_size, void* d_ws, size_t ws_size,
                              hipStream_t stream) {
  const float* q    = (const float*)d_in[0];
  const float* k    = (const float*)d_in[1];
  const float* v    = (const float*)d_in[2];
  const float* proj = (const float*)d_in[3];
  float* out = (float*)d_out;
  float* ws  = (float*)d_ws;

  float*    partialMax = ws;                       // 2048
  float*    kvPart     = ws + 4096;                // 2048*2048
  float*    ksPart     = kvPart + 4194304;         // 2048*32
  float*    vsPart     = ksPart + 65536;           // 2048*64
  float*    ksF        = vsPart + 131072;          // 64*32 (pad 2048)
  float*    kvF        = ksF + 2048;               // 64*2048
  unsigned* pfH        = (unsigned*)(kvF + 131072);// 4*64 uint4 = 1024 words
  unsigned* pfL        = pfH + 1024;               // 1024
  unsigned* kfH        = pfL + 1024;               // 64*4*64 uint4 = 65536 words
  unsigned* kfL        = kfH + 65536;              // 65536

  kfrag_proj<<<1, 256, 0, stream>>>(proj, (uint4*)pfH, (uint4*)pfL);
  k12_kv<<<K12_BLOCKS, 512, 0, stream>>>(k, v, (uint4*)pfH, (uint4*)pfL,
                                         kvPart, ksPart, vsPart, partialMax);
  k2b_sum<<<BH*8, 256, 0, stream>>>(partialMax, kvPart, ksPart, vsPart,
                                    kvF, ksF);
  k2c_frag<<<BH, 256, 0, stream>>>(kvF, (uint4*)kfH, (uint4*)kfL);
  k3_out<<<NROWS / 256, 256, 0, stream>>>(q, (uint4*)pfH, (uint4*)pfL,
                                          (uint4*)kfH, (uint4*)kfL, ksF, out);
}

// Round 24
// 146.001 us; speedup vs baseline: 1.1549x; 1.0069x over previous
//
#include <hip/hip_runtime.h>
#include <hip/hip_bf16.h>
#include <math.h>

#define BH 64
#define NN 8192
#define DD 64
#define MM 32

#define NROWS (BH*NN)            // 524288
#define NORMC 0.35355339059327379f   // 64^-0.25
#define RATIO 0.17677669529663689f   // 32^-0.5
#define EPSK  1e-4f
#define DIAGC 0.0625f                // 0.5 * 64^-0.5

#define CPB 32                   // chunks per batch
#define CHUNK 256                // rows per chunk (8 waves x 32 rows)
#define K12_BLOCKS (BH*CPB)      // 2048 blocks x 512 threads

typedef __attribute__((ext_vector_type(8))) short short8;
typedef __attribute__((ext_vector_type(4))) float f32x4;

union FragU { uint4 u; short8 s; };

// packed fp32x2 -> bf16x2 (round-nearest-even, HW conversion)
__device__ __forceinline__ unsigned pkbf(float a, float b) {
  union { __hip_bfloat162 b2; unsigned u; } r;
  r.b2 = __float22bfloat162_rn(make_float2(a, b));
  return r.u;
}
// packed lo-residuals given the packed hi word (hi values via bit-mask)
__device__ __forceinline__ unsigned pklo(float a, float b, unsigned h) {
  const float ha = __uint_as_float(h << 16);
  const float hb = __uint_as_float(h & 0xffff0000u);
  return pkbf(a - ha, b - hb);
}
// 8 fp32 -> hi/lo bf16x8 fragments (split: x = hi + lo)
__device__ __forceinline__ void cvt8(const float* f, FragU& hi, FragU& lo) {
  unsigned hw[4], lw[4];
  #pragma unroll
  for (int p = 0; p < 4; ++p) {
    hw[p] = pkbf(f[2*p], f[2*p+1]);
    lw[p] = pklo(f[2*p], f[2*p+1], hw[p]);
  }
  hi.u = make_uint4(hw[0], hw[1], hw[2], hw[3]);
  lo.u = make_uint4(lw[0], lw[1], lw[2], lw[3]);
}

#define MFMA(a,b,c) __builtin_amdgcn_mfma_f32_16x16x32_bf16((a),(b),(c),0,0,0)

__device__ __forceinline__ float wave_max(float v) {
  #pragma unroll
  for (int off = 32; off > 0; off >>= 1)
    v = fmaxf(v, __shfl_down(v, off, 64));
  return v;
}

// inline proj B-fragments (per-lane; proj is 8KB, L2-resident after warmup)
__device__ __forceinline__ void load_proj_frags(
    const float* __restrict__ proj, int lr, int lg,
    FragU (&pbH)[2][2], FragU (&pbL)[2][2]) {
  #pragma unroll
  for (int mt = 0; mt < 2; ++mt)
    #pragma unroll
    for (int ks = 0; ks < 2; ++ks) {
      float f[8];
      #pragma unroll
      for (int j = 0; j < 8; ++j)
        f[j] = proj[(mt*16 + lr)*DD + ks*32 + lg*8 + j];
      cvt8(f, pbH[mt][ks], pbL[mt][ks]);
    }
}

// ---------------- K12: FUSED — dash MFMA -> E' (LDS bf16) -> kv MFMA --------
// R24 = R23 (best) with proj fragments built inline (kfrag_proj dispatch
// removed; 32 scalar dword loads per block hide under the first k loads).
__global__ __launch_bounds__(512, 4) void k12_kv(
    const float* __restrict__ k, const float* __restrict__ v,
    const float* __restrict__ proj,
    float* __restrict__ kvPart, float* __restrict__ ksPart,
    float* __restrict__ vsPart, float* __restrict__ partialMax)
{
  __shared__ float red[10240];     // 40960 B: 8x5KB staging, then reductions
  const int t = threadIdx.x;       // 0..511
  const int w = t >> 6, l = t & 63;
  const int lr = l & 15, lg = l >> 4;
  const int blk = blockIdx.x;
  const int b = blk >> 5, c = blk & (CPB - 1);
  const size_t nrow0 = (size_t)b * NN + (size_t)c * CHUNK + (size_t)w * 32;

  ushort* eh = (ushort*)red + w * 2560;   // [32 m][40] hi  (2560B/wave)
  ushort* el = eh + 1280;                 // [32 m][40] lo

  FragU pbH[2][2], pbL[2][2];      // persistent proj fragments (inline build)
  load_proj_frags(proj, lr, lg, pbH, pbL);

  f32x4 accK[2][4];
  #pragma unroll
  for (int mt = 0; mt < 2; ++mt)
    #pragma unroll
    for (int dt = 0; dt < 4; ++dt)
      accK[mt][dt] = (f32x4){0.f, 0.f, 0.f, 0.f};
  float ksacc0 = 0.f, ksacc1 = 0.f;
  float vsum[4] = {0.f, 0.f, 0.f, 0.f};
  float tmax = -3.4e38f;

  // ---- phase A: E' for this wave's 32 rows (MFMA dash), staged to LDS
  #pragma unroll
  for (int rt = 0; rt < 2; ++rt) {
    float sq = 0.f;
    f32x4 a0 = {0.f,0.f,0.f,0.f}, a1 = {0.f,0.f,0.f,0.f};
    #pragma unroll
    for (int ks = 0; ks < 2; ++ks) {
      const float4* src = (const float4*)(k + (nrow0 + rt*16 + lr)*DD + ks*32 + lg*8);
      float4 x0 = src[0], x1 = src[1];
      float qv[8] = {x0.x,x0.y,x0.z,x0.w, x1.x,x1.y,x1.z,x1.w};
      #pragma unroll
      for (int j = 0; j < 8; ++j) sq += qv[j]*qv[j];
      FragU aH, aL; cvt8(qv, aH, aL);     // live only inside this ks

      a0 = MFMA(aL.s, pbH[0][ks].s, a0);
      a0 = MFMA(aH.s, pbL[0][ks].s, a0);
      a0 = MFMA(aH.s, pbH[0][ks].s, a0);
      a1 = MFMA(aL.s, pbH[1][ks].s, a1);
      a1 = MFMA(aH.s, pbL[1][ks].s, a1);
      a1 = MFMA(aH.s, pbH[1][ks].s, a1);
    }
    sq += __shfl_xor(sq, 16, 64);
    sq += __shfl_xor(sq, 32, 64);
    float e0v[4], e1v[4];
    #pragma unroll
    for (int reg = 0; reg < 4; ++reg) {
      const float diag = DIAGC * __shfl(sq, lg*4 + reg, 64);
      const float d0 = a0[reg] * NORMC;
      const float d1 = a1[reg] * NORMC;
      tmax = fmaxf(tmax, fmaxf(d0, d1));
      e0v[reg] = __expf(d0 - diag);
      e1v[reg] = __expf(d1 - diag);
      ksacc0 += e0v[reg];                // col m = lr
      ksacc1 += e1v[reg];                // col m = lr+16
    }
    const int nloc = rt*16 + lg*4;       // 4 consecutive ushorts, 4B-aligned
    const unsigned h00 = pkbf(e0v[0], e0v[1]), h01 = pkbf(e0v[2], e0v[3]);
    const unsigned l00 = pklo(e0v[0], e0v[1], h00), l01 = pklo(e0v[2], e0v[3], h01);
    const unsigned h10 = pkbf(e1v[0], e1v[1]), h11 = pkbf(e1v[2], e1v[3]);
    const unsigned l10 = pklo(e1v[0], e1v[1], h10), l11 = pklo(e1v[2], e1v[3], h11);
    *(unsigned*)(eh + lr*40      + nloc)     = h00;
    *(unsigned*)(eh + lr*40      + nloc + 2) = h01;
    *(unsigned*)(el + lr*40      + nloc)     = l00;
    *(unsigned*)(el + lr*40      + nloc + 2) = l01;
    *(unsigned*)(eh + (lr+16)*40 + nloc)     = h10;
    *(unsigned*)(eh + (lr+16)*40 + nloc + 2) = h11;
    *(unsigned*)(el + (lr+16)*40 + nloc)     = l10;
    *(unsigned*)(el + (lr+16)*40 + nloc + 2) = l11;
  }

  // ---- phase B: kv += E'^T x v via MFMA (A from LDS, B from global)
  #pragma unroll
  for (int dt = 0; dt < 4; ++dt) {
    float vv[8];
    #pragma unroll
    for (int j = 0; j < 8; ++j)
      vv[j] = v[(nrow0 + lg*8 + j)*DD + dt*16 + lr];
    vsum[dt] += vv[0]+vv[1]+vv[2]+vv[3]+vv[4]+vv[5]+vv[6]+vv[7];
    FragU bHv, bLv; cvt8(vv, bHv, bLv);
    #pragma unroll
    for (int mt = 0; mt < 2; ++mt) {
      FragU aHk, aLk;
      aHk.u = *(const uint4*)(eh + (mt*16 + lr)*40 + lg*8);
      aLk.u = *(const uint4*)(el + (mt*16 + lr)*40 + lg*8);
      accK[mt][dt] = MFMA(aLk.s, bHv.s, accK[mt][dt]);
      accK[mt][dt] = MFMA(aHk.s, bLv.s, accK[mt][dt]);
      accK[mt][dt] = MFMA(aHk.s, bHv.s, accK[mt][dt]);
    }
  }

  // ---- epilogue: wave reductions, then two-stage cross-wave reduction
  tmax = wave_max(tmax);
  ksacc0 += __shfl_xor(ksacc0, 16, 64);
  ksacc0 += __shfl_xor(ksacc0, 32, 64);
  ksacc1 += __shfl_xor(ksacc1, 16, 64);
  ksacc1 += __shfl_xor(ksacc1, 32, 64);
  #pragma unroll
  for (int dt = 0; dt < 4; ++dt) {
    vsum[dt] += __shfl_xor(vsum[dt], 16, 64);
    vsum[dt] += __shfl_xor(vsum[dt], 32, 64);
  }
  __syncthreads();                 // all staging reads done; red reusable
  if (w < 4) {
    #pragma unroll
    for (int mt = 0; mt < 2; ++mt)
      #pragma unroll
      for (int dt = 0; dt < 4; ++dt)
        #pragma unroll
        for (int reg = 0; reg < 4; ++reg)
          red[((mt*16 + lg*4 + reg)*64 + dt*16 + lr)*4 + w] = accK[mt][dt][reg];
  }
  if (l == 0) red[8192 + w] = tmax;
  __syncthreads();
  if (w >= 4) {
    #pragma unroll
    for (int mt = 0; mt < 2; ++mt)
      #pragma unroll
      for (int dt = 0; dt < 4; ++dt)
        #pragma unroll
        for (int reg = 0; reg < 4; ++reg)
          red[((mt*16 + lg*4 + reg)*64 + dt*16 + lr)*4 + (w-4)] += accK[mt][dt][reg];
  }
  __syncthreads();
  if (t == 0) {
    float mx = red[8192];
    #pragma unroll
    for (int i = 1; i < 8; ++i) mx = fmaxf(mx, red[8192+i]);
    partialMax[blk] = mx;
  }
  #pragma unroll
  for (int ii = 0; ii < 4; ++ii) {
    const int o = t + 512 * ii;
    const float4 r4 = *(const float4*)&red[o*4];
    kvPart[(size_t)blk * 2048 + o] = r4.x + r4.y + r4.z + r4.w;
  }
  __syncthreads();
  if (l < 16) {
    red[w*32 + lr]        = ksacc0;
    red[w*32 + 16 + lr]   = ksacc1;
    #pragma unroll
    for (int dt = 0; dt < 4; ++dt)
      red[256 + w*64 + dt*16 + lr] = vsum[dt];
  }
  __syncthreads();
  if (t < 32) {
    float s = 0.f;
    #pragma unroll
    for (int ww = 0; ww < 8; ++ww) s += red[ww*32 + t];
    ksPart[blk*32 + t] = s;
  }
  if (t < 64) {
    float s = 0.f;
    #pragma unroll
    for (int ww = 0; ww < 8; ++ww) s += red[256 + ww*64 + t];
    vsPart[blk*64 + t] = s;
  }
}

// ---------------- K2b_sum: gmax (redundant per block) + parallel reduction --
__global__ __launch_bounds__(256) void k2b_sum(
    const float* __restrict__ partialMax,
    const float* __restrict__ kvPart, const float* __restrict__ ksPart,
    const float* __restrict__ vsPart,
    float* __restrict__ kvF, float* __restrict__ ksF)
{
  __shared__ float vsumL[64];
  __shared__ float wred[4];
  const int blk = blockIdx.x;
  const int b = blk >> 3, seg = blk & 7;
  const int t = threadIdx.x;
  float mx = -3.4e38f;
  for (int i = t; i < K12_BLOCKS; i += 256) mx = fmaxf(mx, partialMax[i]);
  mx = wave_max(mx);
  if ((t & 63) == 0) wred[t >> 6] = mx;
  if (t < 64) {
    float s = 0.f;
    #pragma unroll 4
    for (int c = 0; c < CPB; ++c)
      s += vsPart[(b * CPB + c) * 64 + t];
    vsumL[t] = s;
  }
  __syncthreads();
  const float scale =
      __expf(-fmaxf(fmaxf(wred[0], wred[1]), fmaxf(wred[2], wred[3])));
  const int o = seg * 256 + t;
  float s = 0.f;
  #pragma unroll 4
  for (int c = 0; c < CPB; ++c)
    s += kvPart[((size_t)(b * CPB + c)) * 2048 + o];
  kvF[b * 2048 + o] = RATIO * (scale * s + EPSK * vsumL[o & 63]);
  if (seg == 0 && t < 32) {
    float ks = 0.f;
    #pragma unroll 4
    for (int c = 0; c < CPB; ++c)
      ks += ksPart[(b * CPB + c) * 32 + t];
    ksF[b * 32 + t] = RATIO * (scale * ks + EPSK * (float)NN);
  }
}

// ---------------- K2c: kvF -> kv B-fragments --------------------------------
__global__ __launch_bounds__(256) void k2c_frag(
    const float* __restrict__ kvF,
    uint4* __restrict__ kfH, uint4* __restrict__ kfL)
{
  __shared__ float kvL[2048];
  const int b = blockIdx.x, t = threadIdx.x;
  #pragma unroll
  for (int ii = 0; ii < 8; ++ii)
    kvL[t + 256*ii] = kvF[b*2048 + t + 256*ii];
  __syncthreads();
  const int l = t & 63, dt = t >> 6;
  const int lr = l & 15, lg = l >> 4;
  float f[8];
  #pragma unroll
  for (int j = 0; j < 8; ++j)
    f[j] = kvL[(lg*8 + j)*64 + dt*16 + lr];
  FragU hi, lo; cvt8(f, hi, lo);
  kfH[(b*4 + dt)*64 + l] = hi.u;
  kfL[(b*4 + dt)*64 + l] = lo.u;
}

// ---------------- K3: dash MFMA -> softmax -> num MFMA (barrier-free) -------
__global__ __launch_bounds__(256, 4) void k3_out(
    const float* __restrict__ q, const float* __restrict__ proj,
    const uint4* __restrict__ kfH, const uint4* __restrict__ kfL,
    const float* __restrict__ ksF, float* __restrict__ out)
{
  __shared__ float dashL[256][36];   // fp32 dash; reused per-row as packed pstar
  __shared__ float ssqL[256][4];
  const int t = threadIdx.x;
  const int w = t >> 6, l = t & 63;
  const int lr = l & 15, lg = l >> 4;
  const int b = blockIdx.x >> 5;
  const size_t rowBase = (size_t)blockIdx.x * 256;
  const int wrb = w * 64;

  FragU pbH[2][2], pbL[2][2];
  load_proj_frags(proj, lr, lg, pbH, pbL);

  // phase A
  #pragma unroll
  for (int rt = 0; rt < 4; ++rt) {
    const int rrow = wrb + rt*16 + lr;
    f32x4 acc0 = {0.f,0.f,0.f,0.f}, acc1 = {0.f,0.f,0.f,0.f};
    float sq = 0.f;
    #pragma unroll
    for (int ks = 0; ks < 2; ++ks) {
      const float4* src = (const float4*)(q + (rowBase + rrow)*DD + ks*32 + lg*8);
      float4 a0 = src[0], a1 = src[1];
      float qv[8] = {a0.x,a0.y,a0.z,a0.w, a1.x,a1.y,a1.z,a1.w};
      #pragma unroll
      for (int j = 0; j < 8; ++j) sq += qv[j]*qv[j];
      FragU aH, aL; cvt8(qv, aH, aL);
      acc0 = MFMA(aL.s, pbH[0][ks].s, acc0);
      acc0 = MFMA(aH.s, pbL[0][ks].s, acc0);
      acc0 = MFMA(aH.s, pbH[0][ks].s, acc0);
      acc1 = MFMA(aL.s, pbH[1][ks].s, acc1);
      acc1 = MFMA(aH.s, pbL[1][ks].s, acc1);
      acc1 = MFMA(aH.s, pbH[1][ks].s, acc1);
    }
    ssqL[rrow][lg] = sq;
    #pragma unroll
    for (int reg = 0; reg < 4; ++reg) {
      dashL[wrb + rt*16 + lg*4 + reg][lr]      = acc0[reg];
      dashL[wrb + rt*16 + lg*4 + reg][16 + lr] = acc1[reg];
    }
  }

  // softmax phase: thread t owns row t (same wave as its stripe: no barrier)
  {
    float dv[32];
    const float4* dr = (const float4*)&dashL[t][0];
    #pragma unroll
    for (int i = 0; i < 8; ++i) {
      float4 v4 = dr[i];
      dv[4*i]=v4.x; dv[4*i+1]=v4.y; dv[4*i+2]=v4.z; dv[4*i+3]=v4.w;
    }
    const float ssq = ssqL[t][0]+ssqL[t][1]+ssqL[t][2]+ssqL[t][3];
    float mx = -3.4e38f;
    #pragma unroll
    for (int m = 0; m < MM; ++m) { dv[m] *= NORMC; mx = fmaxf(mx, dv[m]); }
    const float sub = DIAGC * ssq + mx;
    const float* __restrict__ ksb = ksF + b * 32;
    float den = 0.f;
    #pragma unroll
    for (int m = 0; m < MM; ++m) {
      dv[m] = RATIO * (__expf(dv[m] - sub) + EPSK);
      den = fmaf(dv[m], ksb[m], den);
    }
    const float inv = 1.0f / den;
    unsigned hiw[16], low[16];
    #pragma unroll
    for (int u = 0; u < 16; ++u) {
      const float x0 = dv[2*u] * inv, x1 = dv[2*u+1] * inv;
      hiw[u] = pkbf(x0, x1);
      low[u] = pklo(x0, x1, hiw[u]);
    }
    uint4* pr = (uint4*)&dashL[t][0];   // overwrite own row only
    pr[0] = make_uint4(hiw[0],hiw[1],hiw[2],hiw[3]);
    pr[1] = make_uint4(hiw[4],hiw[5],hiw[6],hiw[7]);
    pr[2] = make_uint4(hiw[8],hiw[9],hiw[10],hiw[11]);
    pr[3] = make_uint4(hiw[12],hiw[13],hiw[14],hiw[15]);
    pr[4] = make_uint4(low[0],low[1],low[2],low[3]);
    pr[5] = make_uint4(low[4],low[5],low[6],low[7]);
    pr[6] = make_uint4(low[8],low[9],low[10],low[11]);
    pr[7] = make_uint4(low[12],low[13],low[14],low[15]);
  }

  // phase B: out = pstar · kv (K=32, one k-step, 3 comp terms)
  FragU kbH[4], kbL[4];
  #pragma unroll
  for (int dt = 0; dt < 4; ++dt) {
    kbH[dt].u = kfH[(b*4 + dt)*64 + l];
    kbL[dt].u = kfL[(b*4 + dt)*64 + l];
  }
  #pragma unroll
  for (int rt = 0; rt < 4; ++rt) {
    const uint4* pr = (const uint4*)&dashL[wrb + rt*16 + lr][0];
    FragU aH, aL;
    aH.u = pr[lg];
    aL.u = pr[4 + lg];
    #pragma unroll
    for (int dt = 0; dt < 4; ++dt) {
      f32x4 o = {0.f,0.f,0.f,0.f};
      o = MFMA(aL.s, kbH[dt].s, o);
      o = MFMA(aH.s, kbL[dt].s, o);
      o = MFMA(aH.s, kbH[dt].s, o);
      float* ob = out + (rowBase + wrb + rt*16 + lg*4)*DD + dt*16 + lr;
      ob[0]      = o[0];
      ob[DD]     = o[1];
      ob[2*DD]   = o[2];
      ob[3*DD]   = o[3];
    }
  }
}

// ---------------- host ------------------------------------------------------
extern "C" void kernel_launch(void* const* d_in, const int* in_sizes, int n_in,
                              void* d_out, int out_size, void* d_ws, size_t ws_size,
                              hipStream_t stream) {
  const float* q    = (const float*)d_in[0];
  const float* k    = (const float*)d_in[1];
  const float* v    = (const float*)d_in[2];
  const float* proj = (const float*)d_in[3];
  float* out = (float*)d_out;
  float* ws  = (float*)d_ws;

  float*    partialMax = ws;                       // 2048
  float*    kvPart     = ws + 4096;                // 2048*2048
  float*    ksPart     = kvPart + 4194304;         // 2048*32
  float*    vsPart     = ksPart + 65536;           // 2048*64
  float*    ksF        = vsPart + 131072;          // 64*32 (pad 2048)
  float*    kvF        = ksF + 2048;               // 64*2048
  unsigned* kfH        = (unsigned*)(kvF + 131072);// 64*4*64 uint4 = 65536 words
  unsigned* kfL        = kfH + 65536;              // 65536

  k12_kv<<<K12_BLOCKS, 512, 0, stream>>>(k, v, proj,
                                         kvPart, ksPart, vsPart, partialMax);
  k2b_sum<<<BH*8, 256, 0, stream>>>(partialMax, kvPart, ksPart, vsPart,
                                    kvF, ksF);
  k2c_frag<<<BH, 256, 0, stream>>>(kvF, (uint4*)kfH, (uint4*)kfL);
  k3_out<<<NROWS / 256, 256, 0, stream>>>(q, proj,
                                          (uint4*)kfH, (uint4*)kfL, ksF, out);
}